// Round 6
// baseline (527.662 us; speedup 1.0000x reference)
//
#include <hip/hip_runtime.h>
#include <math.h>

// ---------------------------------------------------------------------------
// IG_RGCN forward on MI355X. Round 10: barrier-free streaming embed GEMM +
// vectorized combines.
//  - embed_gemm: K=128 -> full B resident in 32KB LDS (frag-ordered), staged
//    once; each wave grid-strides over 16-row tiles with ZERO in-loop
//    barriers (agg-style continuous memory issue). Fused tss|rs gather kept.
//  - combine1/combine2: float4-vectorized, 8 nodes/block (was scalar 4B).
//  - fc1/fc2/fc3_attn/agg/CSR unchanged from round 9 (522.5 us).
// ---------------------------------------------------------------------------

typedef short s16x8 __attribute__((ext_vector_type(8)));
typedef float f32x4 __attribute__((ext_vector_type(4)));

__device__ __forceinline__ ushort f2bf(float f) {
  unsigned u = __float_as_uint(f);
  return (ushort)((u + 0x7FFFu + ((u >> 16) & 1u)) >> 16);
}
__device__ __forceinline__ float bf2f(unsigned hbits) {
  return __uint_as_float(hbits << 16);
}
__device__ __forceinline__ unsigned pack2(float lo, float hi) {
  return (unsigned)f2bf(lo) | ((unsigned)f2bf(hi) << 16);
}

// ---- one-shot weight prep: 8 tensors, W[r][K][128] fp32 -> Wt[r][128][K] bf16
struct PrepAll {
  const float* src[8];
  ushort* dst[8];
  int K[8];
  int total[8];   // R*K*128
};

__global__ __launch_bounds__(256) void prep_all(PrepAll P)
{
  int t = blockIdx.z;
  int off = blockIdx.x * 256 + threadIdx.x;
  if (off >= P.total[t]) return;
  int K = P.K[t];
  int k = off % K;
  int n = (off / K) & 127;
  int r = off / (K * 128);
  P.dst[t][off] = f2bf(P.src[t][((size_t)r * K + k) * 128 + n]);
}

// ---- barrier-free streaming embed: feat0 = bf16[x@W+b | tss | rs]
// Full B (128x128) in LDS frag-ordered; waves grid-stride 16-row tiles.
__global__ __launch_bounds__(256) void embed_gemm(
    const float* __restrict__ A, const ushort* __restrict__ Wt,
    const float* __restrict__ bias, ushort* __restrict__ C, int M, int nt,
    const int* __restrict__ gnid, const float* __restrict__ gtss,
    const float* __restrict__ grs)
{
  __shared__ __align__(16) ushort Bs[2048 * 8];   // 32 KB: full B
  const int tid = threadIdx.x;
  const int lane = tid & 63;
  const int m16 = lane & 15, quad = lane >> 4;

  // stage full B: Bs[(f*8+j)*64+lane] <- Wt[col=j*16+m16][k=f*32+quad*8 ..+8]
  #pragma unroll
  for (int i = 0; i < 8; ++i) {
    int q = tid + 256 * i;
    int col = ((q >> 6) & 7) * 16 + (q & 15);
    int kk  = (q >> 9) * 32 + ((q >> 4) & 3) * 8;
    *(uint4*)&Bs[q * 8] = *(const uint4*)(Wt + (size_t)col * 128 + kk);
  }
  __syncthreads();

  float bcol[8];
  #pragma unroll
  for (int j = 0; j < 8; ++j) bcol[j] = bias[j * 16 + m16];

  const int gwave = blockIdx.x * 4 + (tid >> 6);
  const int nwaves = gridDim.x * 4;

  for (int t = gwave; t < nt; t += nwaves) {
    const int row0 = t * 16;
    const int row = row0 + m16;
    const bool rowOK = row < M;

    uint4 pk[4];
    #pragma unroll
    for (int f = 0; f < 4; ++f) {
      uint4 v = make_uint4(0u, 0u, 0u, 0u);
      if (rowOK) {
        float4 fa = *(const float4*)(A + (size_t)row * 128 + f * 32 + quad * 8);
        float4 fb = *(const float4*)(A + (size_t)row * 128 + f * 32 + quad * 8 + 4);
        v.x = pack2(fa.x, fa.y); v.y = pack2(fa.z, fa.w);
        v.z = pack2(fb.x, fb.y); v.w = pack2(fb.z, fb.w);
      }
      pk[f] = v;
    }

    f32x4 acc[8];
    #pragma unroll
    for (int j = 0; j < 8; ++j)
      #pragma unroll
      for (int p = 0; p < 4; ++p) acc[j][p] = 0.f;

    #pragma unroll
    for (int f = 0; f < 4; ++f) {
      s16x8 af = *(s16x8*)&pk[f];
      #pragma unroll
      for (int j = 0; j < 8; ++j) {
        s16x8 bf = *(const s16x8*)&Bs[((f * 8 + j) * 64 + lane) * 8];
        acc[j] = __builtin_amdgcn_mfma_f32_16x16x32_bf16(af, bf, acc[j], 0, 0, 0);
      }
    }

    #pragma unroll
    for (int p = 0; p < 4; ++p) {
      int grow = row0 + quad * 4 + p;
      if (grow >= M) continue;
      ushort* Crow = C + (size_t)grow * 256;
      #pragma unroll
      for (int j = 0; j < 8; ++j)
        Crow[j * 16 + m16] = f2bf(acc[j][p] + bcol[j]);
    }

    // fused gather: 16 rows x 32 chunks = 512 tasks per tile
    #pragma unroll
    for (int i = 0; i < 8; ++i) {
      int q = lane + 64 * i;
      int grow = row0 + (q >> 5);
      int c = q & 31;
      if (grow >= M) continue;
      int id = gnid[grow];
      float4 v = (c < 16) ? *(const float4*)(gtss + (size_t)id * 64 + c * 4)
                          : *(const float4*)(grs  + (size_t)id * 64 + (c - 16) * 4);
      uint2 g; g.x = pack2(v.x, v.y); g.y = pack2(v.z, v.w);
      *(uint2*)(C + (size_t)grow * 256 + 128 + c * 4) = g;
    }
  }
}

struct GemmDesc {
  const void* A; int lda; size_t aStride; int aKind;   // 0 fp32, 1 bf16, 2 virtual agg
  const ushort* Wt; size_t wStride;                    // [128][K] bf16 per relation
  const float* bias; int biasStride;
  void* C; int ldc; size_t cStride; int cKind;         // 0 fp32, 1 bf16
  int M, K, relu;
  const ushort* aggM; const ushort* aggS; const float* invdeg;
  size_t aggStride; int invStride;
  const int* gnid; const float* gtss; const float* grs;
};

// Load one A fragment (16 bf16 k-values for this lane's row) at k-offset k0.
template<int AKIND>
__device__ __forceinline__ uint4 loadA(const void* Ab, const ushort* AgM,
                                       const ushort* AgS, int lda, int row,
                                       bool rowOK, int k0, int quad, float idg)
{
  uint4 pk = make_uint4(0u, 0u, 0u, 0u);
  if (rowOK) {
    if constexpr (AKIND == 1) {
      pk = *(const uint4*)((const ushort*)Ab + (size_t)row * lda + k0 + quad * 8);
    } else if constexpr (AKIND == 0) {
      const float* A32 = (const float*)Ab;
      float4 fa = *(const float4*)(A32 + (size_t)row * lda + k0 + quad * 8);
      float4 fb = *(const float4*)(A32 + (size_t)row * lda + k0 + quad * 8 + 4);
      pk.x = pack2(fa.x, fa.y); pk.y = pack2(fa.z, fa.w);
      pk.z = pack2(fb.x, fb.y); pk.w = pack2(fb.z, fb.w);
    } else {                               // virtual [mx | sum*invdeg | sum]
      int seg = k0 >> 8;
      int jj  = (k0 & 255) + quad * 8;
      const ushort* Ag = (seg == 0) ? AgM : AgS;
      pk = *(const uint4*)(Ag + (size_t)row * 256 + jj);
      if (seg == 1) {
        pk.x = pack2(bf2f(pk.x & 0xFFFFu) * idg, bf2f(pk.x >> 16) * idg);
        pk.y = pack2(bf2f(pk.y & 0xFFFFu) * idg, bf2f(pk.y >> 16) * idg);
        pk.z = pack2(bf2f(pk.z & 0xFFFFu) * idg, bf2f(pk.z >> 16) * idg);
        pk.w = pack2(bf2f(pk.w & 0xFFFFu) * idg, bf2f(pk.w >> 16) * idg);
      }
    }
  }
  return pk;
}

// Core: C[M,128] = act(A[M,K] @ W + b). 64 rows/block, 16 rows/wave.
template<int K, int AKIND>
__device__ __forceinline__ void gemm_core(const GemmDesc& d, int r, ushort* Bs)
{
  constexpr int NC = K / 64;
  constexpr int NF = K / 32;

  const int tid = threadIdx.x;
  const int wave = tid >> 6, lane = tid & 63;
  const int m16 = lane & 15, quad = lane >> 4;
  const int rowBase = blockIdx.x * 64;
  const int row = rowBase + wave * 16 + m16;
  const bool rowOK = row < d.M;
  const ushort* Wt = d.Wt + (size_t)r * d.wStride;

  const void* Ab = (const char*)d.A +
      (size_t)r * d.aStride * (AKIND == 0 ? sizeof(float) : sizeof(ushort));
  const ushort* AgM = d.aggM + (size_t)r * d.aggStride;
  const ushort* AgS = d.aggS + (size_t)r * d.aggStride;

  float idg = 1.f;
  if (AKIND == 2 && rowOK) idg = d.invdeg[(size_t)r * d.invStride + row];

  f32x4 acc[8];
  #pragma unroll
  for (int j = 0; j < 8; ++j)
    #pragma unroll
    for (int p = 0; p < 4; ++p) acc[j][p] = 0.f;

  uint4 pkAll[(K <= 256) ? NF : 2];
  if constexpr (K <= 256) {
    #pragma unroll
    for (int f = 0; f < NF; ++f)
      pkAll[f] = loadA<AKIND>(Ab, AgM, AgS, d.lda, row, rowOK, f * 32, quad, idg);
  }

  #pragma unroll
  for (int c = 0; c < NC; ++c) {
    if constexpr (K > 256) {
      pkAll[0] = loadA<AKIND>(Ab, AgM, AgS, d.lda, row, rowOK, c * 64,      quad, idg);
      pkAll[1] = loadA<AKIND>(Ab, AgM, AgS, d.lda, row, rowOK, c * 64 + 32, quad, idg);
    }
    if (c) __syncthreads();
    #pragma unroll
    for (int i = 0; i < 4; ++i) {
      int q = tid + 256 * i;
      int col = ((q >> 6) & 7) * 16 + (q & 15);
      int kk  = c * 64 + ((q >> 9) & 1) * 32 + ((q >> 4) & 3) * 8;
      *(uint4*)&Bs[q * 8] = *(const uint4*)(Wt + (size_t)col * K + kk);
    }
    __syncthreads();

    #pragma unroll
    for (int ks = 0; ks < 2; ++ks) {
      uint4 pk = (K <= 256) ? pkAll[c * 2 + ks] : pkAll[ks];
      s16x8 af = *(s16x8*)&pk;
      #pragma unroll
      for (int j = 0; j < 8; ++j) {
        s16x8 bf = *(const s16x8*)&Bs[((ks * 8 + j) * 64 + lane) * 8];
        acc[j] = __builtin_amdgcn_mfma_f32_16x16x32_bf16(af, bf, acc[j], 0, 0, 0);
      }
    }
  }

  const float* bias = d.bias + (size_t)r * d.biasStride;
  float bcol[8];
  #pragma unroll
  for (int j = 0; j < 8; ++j) bcol[j] = bias[j * 16 + m16];

  #pragma unroll
  for (int p = 0; p < 4; ++p) {
    int grow = rowBase + wave * 16 + quad * 4 + p;
    if (grow >= d.M) continue;
    if (d.cKind == 0) {
      float* Crow = (float*)d.C + (size_t)r * d.cStride + (size_t)grow * d.ldc;
      #pragma unroll
      for (int j = 0; j < 8; ++j) {
        float v = acc[j][p] + bcol[j];
        if (d.relu) v = fmaxf(v, 0.f);
        Crow[j * 16 + m16] = v;
      }
    } else {
      ushort* Crow = (ushort*)d.C + (size_t)r * d.cStride + (size_t)grow * d.ldc;
      #pragma unroll
      for (int j = 0; j < 8; ++j) {
        float v = acc[j][p] + bcol[j];
        if (d.relu) v = fmaxf(v, 0.f);
        Crow[j * 16 + m16] = f2bf(v);
      }
    }
  }
}

__global__ __launch_bounds__(256, 4) void gemm_mfma(GemmDesc d0, GemmDesc d1)
{
  __shared__ __align__(16) ushort Bs[1024 * 8];   // 16 KB
  const GemmDesc& d = blockIdx.z ? d1 : d0;
  const int r = blockIdx.y;
  if (d.K == 256)      gemm_core<256, 1>(d, r, Bs);
  else                 gemm_core<768, 2>(d, r, Bs);
}

// ---- fc3 + semantic attention fused (round 9 structure, verified).
__global__ __launch_bounds__(256) void fc3_attn(
    const ushort* __restrict__ inp, size_t aStride,
    const ushort* __restrict__ wt3, size_t wStride,
    const float* __restrict__ b3,
    float* __restrict__ z, size_t zStride, int M,
    const ushort* __restrict__ w1t, const float* __restrict__ b1,
    const float* __restrict__ w2, float* __restrict__ wsum)
{
  __shared__ __align__(16) ushort Zs[64 * 128];   // 16 KB bf16 z tile (swizzled)
  __shared__ __align__(16) ushort Ws[1024 * 8];   // 16 KB B staging

  const int tid = threadIdx.x;
  const int wave = tid >> 6, lane = tid & 63;
  const int m16 = lane & 15, quad = lane >> 4;
  const int r = blockIdx.y;
  const int rowBase = blockIdx.x * 64;
  const int row = rowBase + wave * 16 + m16;
  const bool rowOK = row < M;

  const ushort* A  = inp + (size_t)r * aStride;
  const ushort* Wt = wt3 + (size_t)r * wStride;

  f32x4 acc[8];
  #pragma unroll
  for (int j = 0; j < 8; ++j)
    #pragma unroll
    for (int p = 0; p < 4; ++p) acc[j][p] = 0.f;

  uint4 pkAll[8];
  #pragma unroll
  for (int f = 0; f < 8; ++f) {
    uint4 pk = make_uint4(0u, 0u, 0u, 0u);
    if (rowOK) pk = *(const uint4*)(A + (size_t)row * 256 + f * 32 + quad * 8);
    pkAll[f] = pk;
  }

  #pragma unroll
  for (int c = 0; c < 4; ++c) {
    if (c) __syncthreads();
    #pragma unroll
    for (int i = 0; i < 4; ++i) {
      int q = tid + 256 * i;
      int col = ((q >> 6) & 7) * 16 + (q & 15);
      int kk  = c * 64 + ((q >> 9) & 1) * 32 + ((q >> 4) & 3) * 8;
      *(uint4*)&Ws[q * 8] = *(const uint4*)(Wt + (size_t)col * 256 + kk);
    }
    __syncthreads();
    #pragma unroll
    for (int ks = 0; ks < 2; ++ks) {
      s16x8 af = *(s16x8*)&pkAll[c * 2 + ks];
      #pragma unroll
      for (int j = 0; j < 8; ++j) {
        s16x8 bf = *(const s16x8*)&Ws[((ks * 8 + j) * 64 + lane) * 8];
        acc[j] = __builtin_amdgcn_mfma_f32_16x16x32_bf16(af, bf, acc[j], 0, 0, 0);
      }
    }
  }

  const float* bias = b3 + (size_t)r * 128;
  float bcol[8];
  #pragma unroll
  for (int j = 0; j < 8; ++j) bcol[j] = bias[j * 16 + m16];

  #pragma unroll
  for (int p = 0; p < 4; ++p) {
    int lrow = wave * 16 + quad * 4 + p;
    int grow = rowBase + lrow;
    bool ok = grow < M;
    float* Zr = z + (size_t)r * zStride + (size_t)grow * 128;
    #pragma unroll
    for (int j = 0; j < 8; ++j) {
      float v = ok ? acc[j][p] + bcol[j] : 0.f;
      if (ok) Zr[j * 16 + m16] = v;
      int byte = lrow * 256 + (j * 16 + m16) * 2;
      byte ^= (lrow & 7) << 4;
      *(ushort*)((char*)Zs + byte) = f2bf(v);
    }
  }

  f32x4 acc2[8];
  #pragma unroll
  for (int j = 0; j < 8; ++j)
    #pragma unroll
    for (int p = 0; p < 4; ++p) acc2[j][p] = 0.f;

  const int arow = wave * 16 + m16;
  #pragma unroll
  for (int c = 0; c < 2; ++c) {
    __syncthreads();
    #pragma unroll
    for (int i = 0; i < 4; ++i) {
      int q = tid + 256 * i;
      int col = ((q >> 6) & 7) * 16 + (q & 15);
      int kk  = c * 64 + ((q >> 9) & 1) * 32 + ((q >> 4) & 3) * 8;
      *(uint4*)&Ws[q * 8] = *(const uint4*)(w1t + (size_t)col * 128 + kk);
    }
    __syncthreads();
    #pragma unroll
    for (int ks = 0; ks < 2; ++ks) {
      int kk = c * 64 + ks * 32 + quad * 8;
      int byte = arow * 256 + kk * 2;
      byte ^= (arow & 7) << 4;
      s16x8 af = *(const s16x8*)((const char*)Zs + byte);
      #pragma unroll
      for (int j = 0; j < 8; ++j) {
        s16x8 bf = *(const s16x8*)&Ws[((ks * 8 + j) * 64 + lane) * 8];
        acc2[j] = __builtin_amdgcn_mfma_f32_16x16x32_bf16(af, bf, acc2[j], 0, 0, 0);
      }
    }
  }

  float b1c[8], w2c[8];
  #pragma unroll
  for (int j = 0; j < 8; ++j) { b1c[j] = b1[j * 16 + m16]; w2c[j] = w2[j * 16 + m16]; }

  float local = 0.f;
  #pragma unroll
  for (int p = 0; p < 4; ++p) {
    int grow = rowBase + wave * 16 + quad * 4 + p;
    if (grow >= M) continue;
    #pragma unroll
    for (int j = 0; j < 8; ++j)
      local += tanhf(acc2[j][p] + b1c[j]) * w2c[j];
  }
  #pragma unroll
  for (int o = 32; o > 0; o >>= 1) local += __shfl_down(local, o);
  __shared__ float red[4];
  if (lane == 0) red[wave] = local;
  __syncthreads();
  if (tid == 0) atomicAdd(&wsum[r], red[0] + red[1] + red[2] + red[3]);
}

// ---------------- CSR build (batched over R=3 relations) ----------------
__global__ void count_deg(const int* __restrict__ edst, int E, int N, int* __restrict__ deg)
{
  int e = blockIdx.x * blockDim.x + threadIdx.x;
  int r = blockIdx.y;
  if (e < E) atomicAdd(&deg[r * N + edst[(size_t)r * E + e]], 1);
}

// per-relation exclusive scan (blockIdx.y = r), 4096 elems/iter.
__global__ __launch_bounds__(1024) void scan_kernel(
    const int* __restrict__ deg, int* __restrict__ rowptr,
    int* __restrict__ cursor, int N)
{
  const int r = blockIdx.y;
  const int* dg = deg + (size_t)r * N;
  int* rp  = rowptr + (size_t)r * (N + 1);
  int* cur = cursor + (size_t)r * N;

  __shared__ int wtot[16];
  __shared__ int chunk_total_s;
  const int tid = threadIdx.x, lane = tid & 63, wid = tid >> 6;
  int running = 0;
  for (int base = 0; base < N; base += 4096) {
    int i0 = base + tid * 4;
    int d0 = 0, d1 = 0, d2 = 0, d3 = 0;
    if (i0 < N) {
      if (i0 + 3 < N) { int4 t = *(const int4*)(dg + i0); d0 = t.x; d1 = t.y; d2 = t.z; d3 = t.w; }
      else { d0 = dg[i0]; if (i0+1 < N) d1 = dg[i0+1]; if (i0+2 < N) d2 = dg[i0+2]; }
    }
    int tsum = d0 + d1 + d2 + d3;
    int incl = tsum;
    #pragma unroll
    for (int o = 1; o < 64; o <<= 1) {
      int t = __shfl_up(incl, o);
      if (lane >= o) incl += t;
    }
    if (lane == 63) wtot[wid] = incl;
    __syncthreads();
    if (wid == 0 && lane < 16) {
      int t = wtot[lane];
      int inc = t;
      #pragma unroll
      for (int o = 1; o < 16; o <<= 1) {
        int u = __shfl_up(inc, o);
        if (lane >= o) inc += u;
      }
      wtot[lane] = inc - t;
      if (lane == 15) chunk_total_s = inc;
    }
    __syncthreads();
    int excl = running + wtot[wid] + (incl - tsum);
    if (i0 < N) {
      int e1 = excl + d0, e2 = e1 + d1, e3 = e2 + d2;
      if (i0 + 3 < N) {
        *(int4*)(rp + i0) = make_int4(excl, e1, e2, e3);
        *(int4*)(cur + i0) = make_int4(0, 0, 0, 0);
      } else {
        rp[i0] = excl; cur[i0] = 0;
        if (i0+1 < N) { rp[i0+1] = e1; cur[i0+1] = 0; }
        if (i0+2 < N) { rp[i0+2] = e2; cur[i0+2] = 0; }
      }
    }
    running += chunk_total_s;
    __syncthreads();
  }
  if (tid == 0) rp[N] = running;
}

__global__ void fill_csr(const int* __restrict__ esrc, const int* __restrict__ edst,
                         int E, int N, const int* __restrict__ rowptr,
                         int* __restrict__ cursor, int* __restrict__ csr)
{
  int e = blockIdx.x * blockDim.x + threadIdx.x;
  int r = blockIdx.y;
  if (e >= E) return;
  int dn = edst[(size_t)r * E + e];
  int pos = atomicAdd(&cursor[r * N + dn], 1);
  csr[(size_t)r * E + rowptr[(size_t)r * (N + 1) + dn] + pos] = esrc[(size_t)r * E + e];
}

// one wave per (relation, chunk-local dst node): bf16 gather, x4-unrolled ILP
__global__ __launch_bounds__(256) void agg_kernel(
    const ushort* __restrict__ feat, const int* __restrict__ csr,
    const int* __restrict__ rowptr, int N, int c0, int cr, int CH, int E,
    ushort* __restrict__ aggS, ushort* __restrict__ aggM, float* __restrict__ invdeg)
{
  const int wid = threadIdx.x >> 6, lane = threadIdx.x & 63;
  const int node = blockIdx.x * 4 + wid;
  if (node >= cr) return;
  const size_t rp = (size_t)blockIdx.y * (N + 1) + c0 + node;
  const int o = blockIdx.y * CH + node;
  const int start = rowptr[rp], end = rowptr[rp + 1];
  const int* ecsr = csr + (size_t)blockIdx.y * E;
  const int j = lane * 4;
  float s0 = 0.f, s1 = 0.f, s2 = 0.f, s3 = 0.f;
  float m0 = -INFINITY, m1 = -INFINITY, m2 = -INFINITY, m3 = -INFINITY;
  int e = start;
  for (; e + 4 <= end; e += 4) {
    int sa = ecsr[e], sb = ecsr[e+1], sc = ecsr[e+2], sd = ecsr[e+3];
    uint2 va = *(const uint2*)(feat + (size_t)sa * 256 + j);
    uint2 vb = *(const uint2*)(feat + (size_t)sb * 256 + j);
    uint2 vc = *(const uint2*)(feat + (size_t)sc * 256 + j);
    uint2 vd = *(const uint2*)(feat + (size_t)sd * 256 + j);
    float a0, a1, a2, a3;
    a0 = bf2f(va.x & 0xFFFFu); a1 = bf2f(va.x >> 16); a2 = bf2f(va.y & 0xFFFFu); a3 = bf2f(va.y >> 16);
    s0 += a0; s1 += a1; s2 += a2; s3 += a3;
    m0 = fmaxf(m0, a0); m1 = fmaxf(m1, a1); m2 = fmaxf(m2, a2); m3 = fmaxf(m3, a3);
    a0 = bf2f(vb.x & 0xFFFFu); a1 = bf2f(vb.x >> 16); a2 = bf2f(vb.y & 0xFFFFu); a3 = bf2f(vb.y >> 16);
    s0 += a0; s1 += a1; s2 += a2; s3 += a3;
    m0 = fmaxf(m0, a0); m1 = fmaxf(m1, a1); m2 = fmaxf(m2, a2); m3 = fmaxf(m3, a3);
    a0 = bf2f(vc.x & 0xFFFFu); a1 = bf2f(vc.x >> 16); a2 = bf2f(vc.y & 0xFFFFu); a3 = bf2f(vc.y >> 16);
    s0 += a0; s1 += a1; s2 += a2; s3 += a3;
    m0 = fmaxf(m0, a0); m1 = fmaxf(m1, a1); m2 = fmaxf(m2, a2); m3 = fmaxf(m3, a3);
    a0 = bf2f(vd.x & 0xFFFFu); a1 = bf2f(vd.x >> 16); a2 = bf2f(vd.y & 0xFFFFu); a3 = bf2f(vd.y >> 16);
    s0 += a0; s1 += a1; s2 += a2; s3 += a3;
    m0 = fmaxf(m0, a0); m1 = fmaxf(m1, a1); m2 = fmaxf(m2, a2); m3 = fmaxf(m3, a3);
  }
  for (; e < end; ++e) {
    int src = ecsr[e];
    uint2 v = *(const uint2*)(feat + (size_t)src * 256 + j);
    float a0 = bf2f(v.x & 0xFFFFu), a1 = bf2f(v.x >> 16);
    float a2 = bf2f(v.y & 0xFFFFu), a3 = bf2f(v.y >> 16);
    s0 += a0; s1 += a1; s2 += a2; s3 += a3;
    m0 = fmaxf(m0, a0); m1 = fmaxf(m1, a1); m2 = fmaxf(m2, a2); m3 = fmaxf(m3, a3);
  }
  if (end == start) { m0 = m1 = m2 = m3 = 0.f; }
  uint2 ps; ps.x = pack2(s0, s1); ps.y = pack2(s2, s3);
  *(uint2*)(aggS + (size_t)o * 256 + j) = ps;
  uint2 pm; pm.x = pack2(m0, m1); pm.y = pack2(m2, m3);
  *(uint2*)(aggM + (size_t)o * 256 + j) = pm;
  if (lane == 0) invdeg[o] = 1.f / fmaxf((float)(end - start), 1.f);
}

// ---------------- combine ----------------
__global__ void beta_kernel(const float* __restrict__ wsum, float invN, float* __restrict__ beta) {
  float w0 = wsum[0] * invN, w1 = wsum[1] * invN, w2 = wsum[2] * invN;
  float m  = fmaxf(w0, fmaxf(w1, w2));
  float e0 = expf(w0 - m), e1 = expf(w1 - m), e2 = expf(w2 - m);
  float s  = e0 + e1 + e2;
  beta[0] = e0 / s; beta[1] = e1 / s; beta[2] = e2 / s;
}

// feat1 = bf16[relu(sum_r beta[r]*z1[r]) | tss[nid] | rs[nid]]; 8 nodes/block
__global__ __launch_bounds__(256) void combine1_kernel(
    const float* __restrict__ z1, const float* __restrict__ beta,
    const float* __restrict__ tss, const float* __restrict__ rs,
    const int* __restrict__ nid, int N, ushort* __restrict__ feat1)
{
  int n = blockIdx.x * 8 + (threadIdx.x >> 5);
  int c = threadIdx.x & 31;
  if (n >= N) return;
  size_t NH = (size_t)N * 128;
  float b0 = beta[0], b1 = beta[1], b2 = beta[2];
  const float* zp = z1 + (size_t)n * 128 + c * 4;
  float4 v0 = *(const float4*)zp;
  float4 v1 = *(const float4*)(zp + NH);
  float4 v2 = *(const float4*)(zp + 2 * NH);
  float wx = fmaxf(b0 * v0.x + b1 * v1.x + b2 * v2.x, 0.f);
  float wy = fmaxf(b0 * v0.y + b1 * v1.y + b2 * v2.y, 0.f);
  float wz = fmaxf(b0 * v0.z + b1 * v1.z + b2 * v2.z, 0.f);
  float ww = fmaxf(b0 * v0.w + b1 * v1.w + b2 * v2.w, 0.f);
  uint2 g; g.x = pack2(wx, wy); g.y = pack2(wz, ww);
  *(uint2*)(feat1 + (size_t)n * 256 + c * 4) = g;
  int id = nid[n];
  float4 t = (c < 16) ? *(const float4*)(tss + (size_t)id * 64 + c * 4)
                      : *(const float4*)(rs  + (size_t)id * 64 + (c - 16) * 4);
  uint2 g2; g2.x = pack2(t.x, t.y); g2.y = pack2(t.z, t.w);
  *(uint2*)(feat1 + (size_t)n * 256 + 128 + c * 4) = g2;
}

// out = sigmoid((sum_r beta[r]*z2[r]) @ pw + pb); 8 nodes/block, width-32 reduce
__global__ __launch_bounds__(256) void combine2_pred(
    const float* __restrict__ z2, const float* __restrict__ beta, int N,
    const float* __restrict__ pw, const float* __restrict__ pb, float* __restrict__ out)
{
  int n = blockIdx.x * 8 + (threadIdx.x >> 5);
  int c = threadIdx.x & 31;
  bool ok = n < N;
  float p = 0.f;
  if (ok) {
    size_t NH = (size_t)N * 128;
    const float* zp = z2 + (size_t)n * 128 + c * 4;
    float4 v0 = *(const float4*)zp;
    float4 v1 = *(const float4*)(zp + NH);
    float4 v2 = *(const float4*)(zp + 2 * NH);
    float4 w = *(const float4*)(pw + c * 4);
    float b0 = beta[0], b1 = beta[1], b2 = beta[2];
    p  = (b0 * v0.x + b1 * v1.x + b2 * v2.x) * w.x;
    p += (b0 * v0.y + b1 * v1.y + b2 * v2.y) * w.y;
    p += (b0 * v0.z + b1 * v1.z + b2 * v2.z) * w.z;
    p += (b0 * v0.w + b1 * v1.w + b2 * v2.w) * w.w;
  }
  #pragma unroll
  for (int o = 16; o > 0; o >>= 1) p += __shfl_down(p, o, 32);
  if (ok && c == 0) out[n] = 1.f / (1.f + expf(-(p + pb[0])));
}

extern "C" void kernel_launch(void* const* d_in, const int* in_sizes, int n_in,
                              void* d_out, int out_size, void* d_ws, size_t ws_size,
                              hipStream_t stream)
{
  const float* x_user  = (const float*)d_in[0];
  const float* tss     = (const float*)d_in[1];
  const float* rs      = (const float*)d_in[2];
  const int* src_nid0  = (const int*)d_in[3];
  const int* src_nid1  = (const int*)d_in[4];
  const int* e0_src    = (const int*)d_in[5];
  const int* e0_dst    = (const int*)d_in[6];
  const int* e1_src    = (const int*)d_in[7];
  const int* e1_dst    = (const int*)d_in[8];
  const float* embed_w = (const float*)d_in[9];
  const float* embed_b = (const float*)d_in[10];
  const float* l1w[3]  = {(const float*)d_in[11], (const float*)d_in[13], (const float*)d_in[15]};
  const float* l1b[3]  = {(const float*)d_in[12], (const float*)d_in[14], (const float*)d_in[16]};
  const float* l2w[3]  = {(const float*)d_in[17], (const float*)d_in[19], (const float*)d_in[21]};
  const float* l2b[3]  = {(const float*)d_in[18], (const float*)d_in[20], (const float*)d_in[22]};
  const float* attn_w1 = (const float*)d_in[23];
  const float* attn_b1 = (const float*)d_in[24];
  const float* attn_w2 = (const float*)d_in[25];
  const float* pred_w  = (const float*)d_in[26];
  const float* pred_b  = (const float*)d_in[27];
  float* out = (float*)d_out;

  const int N0 = in_sizes[0] / 128;
  const int N1 = in_sizes[4];
  const int N2 = out_size;
  const int E0 = in_sizes[5] / 3;
  const int E1 = in_sizes[7] / 3;

  char* wp = (char*)d_ws;
  auto walloc = [&](size_t bytes) {
    char* p = wp; wp += (bytes + 255) & ~(size_t)255; return p;
  };
  ushort* feat0  = (ushort*)walloc((size_t)N0 * 256 * 2);      // bf16
  ushort* inp    = (ushort*)walloc((size_t)3 * N1 * 256 * 2);  // bf16
  float*  z      = (float*)walloc((size_t)3 * N1 * 128 * 4);   // fp32
  ushort* wt_emb = (ushort*)walloc((size_t)128 * 128 * 2);
  ushort* wt_attn = (ushort*)walloc((size_t)128 * 128 * 2);
  ushort* wt_fc1[2], *wt_fc2[2], *wt_fc3[2];
  for (int l = 0; l < 2; ++l) {
    wt_fc1[l] = (ushort*)walloc((size_t)3 * 256 * 128 * 2);
    wt_fc2[l] = (ushort*)walloc((size_t)3 * 768 * 128 * 2);
    wt_fc3[l] = (ushort*)walloc((size_t)3 * 256 * 128 * 2);
  }
  int*   degcnt = (int*)walloc((size_t)3 * N1 * 4);
  int*   rowptr = (int*)walloc((size_t)3 * (N1 + 1) * 4);
  int*   csr    = (int*)walloc((size_t)3 * E0 * 4);
  float* small  = (float*)walloc(256);
  float* wsum = small;
  float* beta = small + 4;
  ushort* feat1 = feat0;

  size_t used = (size_t)(wp - (char*)d_ws);
  size_t avail = (ws_size > used + 65536) ? (ws_size - used - 65536) : 0;
  const size_t per_row = (size_t)3 * (2 * 256 * 2 + 4 + 64);
  int CH = (int)(avail / per_row);
  if (CH > N1) CH = N1;
  if (CH < 1024) CH = 1024;
  ushort* aggS   = (ushort*)walloc((size_t)3 * CH * 256 * 2);
  ushort* aggM   = (ushort*)walloc((size_t)3 * CH * 256 * 2);
  float*  invdeg = (float*)walloc((size_t)3 * CH * 4);
  (void)n_in;

  // ---- weight prep ----
  {
    PrepAll P;
    P.src[0] = embed_w;  P.dst[0] = wt_emb;    P.K[0] = 128; P.total[0] = 128 * 128;
    P.src[1] = attn_w1;  P.dst[1] = wt_attn;   P.K[1] = 128; P.total[1] = 128 * 128;
    P.src[2] = l1w[0];   P.dst[2] = wt_fc1[0]; P.K[2] = 256; P.total[2] = 3 * 256 * 128;
    P.src[3] = l1w[1];   P.dst[3] = wt_fc2[0]; P.K[3] = 768; P.total[3] = 3 * 768 * 128;
    P.src[4] = l1w[2];   P.dst[4] = wt_fc3[0]; P.K[4] = 256; P.total[4] = 3 * 256 * 128;
    P.src[5] = l2w[0];   P.dst[5] = wt_fc1[1]; P.K[5] = 256; P.total[5] = 3 * 256 * 128;
    P.src[6] = l2w[1];   P.dst[6] = wt_fc2[1]; P.K[6] = 768; P.total[6] = 3 * 768 * 128;
    P.src[7] = l2w[2];   P.dst[7] = wt_fc3[1]; P.K[7] = 256; P.total[7] = 3 * 256 * 128;
    prep_all<<<dim3((3 * 768 * 128 + 255) / 256, 1, 8), 256, 0, stream>>>(P);
  }

  // ---- streaming embed ----
  {
    int nt = (N0 + 15) / 16;
    int blocks = 1280;
    if (blocks * 4 > nt) blocks = (nt + 3) / 4;
    embed_gemm<<<blocks, 256, 0, stream>>>(
        x_user, wt_emb, embed_b, feat0, N0, nt, src_nid0, tss, rs);
  }

  GemmDesc dz = {};
  dz.K = 256;

  // ---- two conv layers ----
  for (int layer = 0; layer < 2; ++layer) {
    const ushort* featS = layer ? feat1 : feat0;
    int Nd = layer ? N2 : N1;
    int E  = layer ? E1 : E0;
    const int* es = layer ? e1_src : e0_src;
    const int* ed = layer ? e1_dst : e0_dst;
    const float* const* lb = layer ? l2b : l1b;

    hipMemsetAsync(degcnt, 0, (size_t)3 * Nd * 4, stream);
    count_deg<<<dim3((E + 255) / 256, 3), 256, 0, stream>>>(ed, E, Nd, degcnt);
    scan_kernel<<<dim3(1, 3), 1024, 0, stream>>>(degcnt, rowptr, degcnt, Nd);
    fill_csr<<<dim3((E + 255) / 256, 3), 256, 0, stream>>>(es, ed, E, Nd, rowptr, degcnt, csr);

    for (int c0 = 0; c0 < Nd; c0 += CH) {
      int cr = (Nd - c0 < CH) ? (Nd - c0) : CH;
      agg_kernel<<<dim3((cr + 3) / 4, 3), 256, 0, stream>>>(
          featS, csr, rowptr, Nd, c0, cr, CH, E, aggS, aggM, invdeg);
      GemmDesc d2{};
      d2.A = nullptr; d2.lda = 0; d2.aStride = 0; d2.aKind = 2;
      d2.Wt = wt_fc2[layer]; d2.wStride = (size_t)768 * 128; d2.bias = lb[1]; d2.biasStride = 128;
      d2.C = inp + (size_t)c0 * 256; d2.ldc = 256; d2.cStride = (size_t)Nd * 256; d2.cKind = 1;
      d2.M = cr; d2.K = 768; d2.relu = 1;
      d2.aggM = aggM; d2.aggS = aggS; d2.invdeg = invdeg;
      d2.aggStride = (size_t)CH * 256; d2.invStride = CH;
      GemmDesc d1{};
      d1.A = featS + (size_t)c0 * 256; d1.lda = 256; d1.aStride = 0; d1.aKind = 1;
      d1.Wt = wt_fc1[layer]; d1.wStride = (size_t)256 * 128; d1.bias = lb[0]; d1.biasStride = 128;
      d1.C = inp + 128 + (size_t)c0 * 256; d1.ldc = 256; d1.cStride = (size_t)Nd * 256; d1.cKind = 1;
      d1.M = cr; d1.K = 256; d1.relu = 1;
      d1.aggM = aggM; d1.aggS = aggS; d1.invdeg = invdeg; d1.aggStride = 0; d1.invStride = 0;
      gemm_mfma<<<dim3((cr + 63) / 64, 3, 2), 256, 0, stream>>>(d2, d1);
    }

    hipMemsetAsync(wsum, 0, 3 * sizeof(float), stream);
    fc3_attn<<<dim3((Nd + 63) / 64, 3), 256, 0, stream>>>(
        inp, (size_t)Nd * 256, wt_fc3[layer], (size_t)256 * 128, lb[2],
        z, (size_t)Nd * 128, Nd, wt_attn, attn_b1, attn_w2, wsum);
    beta_kernel<<<1, 1, 0, stream>>>(wsum, 1.0f / (float)Nd, beta);

    if (layer == 0) {
      combine1_kernel<<<(N1 + 7) / 8, 256, 0, stream>>>(z, beta, tss, rs, src_nid1, N1, feat1);
    } else {
      combine2_pred<<<(N2 + 7) / 8, 256, 0, stream>>>(z, beta, N2, pred_w, pred_b, out);
    }
  }
}

// Round 7
// 497.810 us; speedup vs baseline: 1.0600x; 1.0600x over previous
//
#include <hip/hip_runtime.h>
#include <math.h>

// ---------------------------------------------------------------------------
// IG_RGCN forward on MI355X. Round 11: revert embed to phased GEMM (r6's
// barrier-free embed regressed 65->81us); cut dispatch count 22 -> 15.
//  - embed via gemm_core<128,0> (proven 65us, VGPR 48, 0 conflicts).
//  - CSR build unified: 6 (layer,relation) pairs in ONE count/scan/fill set.
//  - beta softmax folded into combine1/combine2 (beta_kernel removed).
//  - one upfront memset covers degcnt + wsum.
//  - fc12 / fc3_attn / agg / vectorized combines unchanged.
// ---------------------------------------------------------------------------

typedef short s16x8 __attribute__((ext_vector_type(8)));
typedef float f32x4 __attribute__((ext_vector_type(4)));

__device__ __forceinline__ ushort f2bf(float f) {
  unsigned u = __float_as_uint(f);
  return (ushort)((u + 0x7FFFu + ((u >> 16) & 1u)) >> 16);
}
__device__ __forceinline__ float bf2f(unsigned hbits) {
  return __uint_as_float(hbits << 16);
}
__device__ __forceinline__ unsigned pack2(float lo, float hi) {
  return (unsigned)f2bf(lo) | ((unsigned)f2bf(hi) << 16);
}

// ---- one-shot weight prep: 8 tensors, W[r][K][128] fp32 -> Wt[r][128][K] bf16
struct PrepAll {
  const float* src[8];
  ushort* dst[8];
  int K[8];
  int total[8];
};

__global__ __launch_bounds__(256) void prep_all(PrepAll P)
{
  int t = blockIdx.z;
  int off = blockIdx.x * 256 + threadIdx.x;
  if (off >= P.total[t]) return;
  int K = P.K[t];
  int k = off % K;
  int n = (off / K) & 127;
  int r = off / (K * 128);
  P.dst[t][off] = f2bf(P.src[t][((size_t)r * K + k) * 128 + n]);
}

struct GemmDesc {
  const void* A; int lda; size_t aStride; int aKind;   // 0 fp32, 1 bf16, 2 virtual agg
  const ushort* Wt; size_t wStride;
  const float* bias; int biasStride;
  void* C; int ldc; size_t cStride; int cKind;         // 0 fp32, 1 bf16
  int M, K, relu;
  const ushort* aggM; const ushort* aggS; const float* invdeg;
  size_t aggStride; int invStride;
  const int* gnid; const float* gtss; const float* grs; // embed-only fused gather
};

template<int AKIND>
__device__ __forceinline__ uint4 loadA(const void* Ab, const ushort* AgM,
                                       const ushort* AgS, int lda, int row,
                                       bool rowOK, int k0, int quad, float idg)
{
  uint4 pk = make_uint4(0u, 0u, 0u, 0u);
  if (rowOK) {
    if constexpr (AKIND == 1) {
      pk = *(const uint4*)((const ushort*)Ab + (size_t)row * lda + k0 + quad * 8);
    } else if constexpr (AKIND == 0) {
      const float* A32 = (const float*)Ab;
      float4 fa = *(const float4*)(A32 + (size_t)row * lda + k0 + quad * 8);
      float4 fb = *(const float4*)(A32 + (size_t)row * lda + k0 + quad * 8 + 4);
      pk.x = pack2(fa.x, fa.y); pk.y = pack2(fa.z, fa.w);
      pk.z = pack2(fb.x, fb.y); pk.w = pack2(fb.z, fb.w);
    } else {                               // virtual [mx | sum*invdeg | sum]
      int seg = k0 >> 8;
      int jj  = (k0 & 255) + quad * 8;
      const ushort* Ag = (seg == 0) ? AgM : AgS;
      pk = *(const uint4*)(Ag + (size_t)row * 256 + jj);
      if (seg == 1) {
        pk.x = pack2(bf2f(pk.x & 0xFFFFu) * idg, bf2f(pk.x >> 16) * idg);
        pk.y = pack2(bf2f(pk.y & 0xFFFFu) * idg, bf2f(pk.y >> 16) * idg);
        pk.z = pack2(bf2f(pk.z & 0xFFFFu) * idg, bf2f(pk.z >> 16) * idg);
        pk.w = pack2(bf2f(pk.w & 0xFFFFu) * idg, bf2f(pk.w >> 16) * idg);
      }
    }
  }
  return pk;
}

// Core: C[M,128] = act(A[M,K] @ W + b). 64 rows/block, 16 rows/wave.
template<int K, int AKIND>
__device__ __forceinline__ void gemm_core(const GemmDesc& d, int r, ushort* Bs)
{
  constexpr int NC = K / 64;
  constexpr int NF = K / 32;

  const int tid = threadIdx.x;
  const int wave = tid >> 6, lane = tid & 63;
  const int m16 = lane & 15, quad = lane >> 4;
  const int rowBase = blockIdx.x * 64;
  const int row = rowBase + wave * 16 + m16;
  const bool rowOK = row < d.M;
  const ushort* Wt = d.Wt + (size_t)r * d.wStride;

  const void* Ab = (const char*)d.A +
      (size_t)r * d.aStride * (AKIND == 0 ? sizeof(float) : sizeof(ushort));
  const ushort* AgM = d.aggM + (size_t)r * d.aggStride;
  const ushort* AgS = d.aggS + (size_t)r * d.aggStride;

  float idg = 1.f;
  if (AKIND == 2 && rowOK) idg = d.invdeg[(size_t)r * d.invStride + row];

  f32x4 acc[8];
  #pragma unroll
  for (int j = 0; j < 8; ++j)
    #pragma unroll
    for (int p = 0; p < 4; ++p) acc[j][p] = 0.f;

  uint4 pkAll[(K <= 256) ? NF : 2];
  if constexpr (K <= 256) {
    #pragma unroll
    for (int f = 0; f < NF; ++f)
      pkAll[f] = loadA<AKIND>(Ab, AgM, AgS, d.lda, row, rowOK, f * 32, quad, idg);
  }

  #pragma unroll
  for (int c = 0; c < NC; ++c) {
    if constexpr (K > 256) {
      pkAll[0] = loadA<AKIND>(Ab, AgM, AgS, d.lda, row, rowOK, c * 64,      quad, idg);
      pkAll[1] = loadA<AKIND>(Ab, AgM, AgS, d.lda, row, rowOK, c * 64 + 32, quad, idg);
    }
    if (c) __syncthreads();
    #pragma unroll
    for (int i = 0; i < 4; ++i) {
      int q = tid + 256 * i;
      int col = ((q >> 6) & 7) * 16 + (q & 15);
      int kk  = c * 64 + ((q >> 9) & 1) * 32 + ((q >> 4) & 3) * 8;
      *(uint4*)&Bs[q * 8] = *(const uint4*)(Wt + (size_t)col * K + kk);
    }
    __syncthreads();

    #pragma unroll
    for (int ks = 0; ks < 2; ++ks) {
      uint4 pk = (K <= 256) ? pkAll[c * 2 + ks] : pkAll[ks];
      s16x8 af = *(s16x8*)&pk;
      #pragma unroll
      for (int j = 0; j < 8; ++j) {
        s16x8 bf = *(const s16x8*)&Bs[((ks * 8 + j) * 64 + lane) * 8];
        acc[j] = __builtin_amdgcn_mfma_f32_16x16x32_bf16(af, bf, acc[j], 0, 0, 0);
      }
    }
  }

  const float* bias = d.bias + (size_t)r * d.biasStride;
  float bcol[8];
  #pragma unroll
  for (int j = 0; j < 8; ++j) bcol[j] = bias[j * 16 + m16];

  #pragma unroll
  for (int p = 0; p < 4; ++p) {
    int grow = rowBase + wave * 16 + quad * 4 + p;
    if (grow >= d.M) continue;
    if (d.cKind == 0) {
      float* Crow = (float*)d.C + (size_t)r * d.cStride + (size_t)grow * d.ldc;
      #pragma unroll
      for (int j = 0; j < 8; ++j) {
        float v = acc[j][p] + bcol[j];
        if (d.relu) v = fmaxf(v, 0.f);
        Crow[j * 16 + m16] = v;
      }
    } else {
      ushort* Crow = (ushort*)d.C + (size_t)r * d.cStride + (size_t)grow * d.ldc;
      #pragma unroll
      for (int j = 0; j < 8; ++j) {
        float v = acc[j][p] + bcol[j];
        if (d.relu) v = fmaxf(v, 0.f);
        Crow[j * 16 + m16] = f2bf(v);
      }
    }
  }

  // fused gather (embed only): C cols 128..255 <- bf16(tss[nid] | rs[nid])
  if constexpr (K == 128) {
    if (d.gnid) {
      #pragma unroll
      for (int i = 0; i < 8; ++i) {
        int q = tid + 256 * i;            // 2048 tasks: 64 rows x 32 chunks
        int grow = rowBase + (q >> 5);
        int c = q & 31;
        if (grow >= d.M) continue;
        int id = d.gnid[grow];
        float4 v = (c < 16) ? *(const float4*)(d.gtss + (size_t)id * 64 + c * 4)
                            : *(const float4*)(d.grs  + (size_t)id * 64 + (c - 16) * 4);
        uint2 g; g.x = pack2(v.x, v.y); g.y = pack2(v.z, v.w);
        *(uint2*)((ushort*)d.C + (size_t)grow * d.ldc + 128 + c * 4) = g;
      }
    }
  }
}

__global__ __launch_bounds__(256, 4) void gemm_mfma(GemmDesc d0, GemmDesc d1)
{
  __shared__ __align__(16) ushort Bs[1024 * 8];   // 16 KB
  const GemmDesc& d = blockIdx.z ? d1 : d0;
  const int r = blockIdx.y;
  if (d.K == 128)      gemm_core<128, 0>(d, r, Bs);
  else if (d.K == 256) gemm_core<256, 1>(d, r, Bs);
  else                 gemm_core<768, 2>(d, r, Bs);
}

// ---- fc3 + semantic attention fused (round 9 structure, verified).
__global__ __launch_bounds__(256) void fc3_attn(
    const ushort* __restrict__ inp, size_t aStride,
    const ushort* __restrict__ wt3, size_t wStride,
    const float* __restrict__ b3,
    float* __restrict__ z, size_t zStride, int M,
    const ushort* __restrict__ w1t, const float* __restrict__ b1,
    const float* __restrict__ w2, float* __restrict__ wsum)
{
  __shared__ __align__(16) ushort Zs[64 * 128];   // 16 KB bf16 z tile (swizzled)
  __shared__ __align__(16) ushort Ws[1024 * 8];   // 16 KB B staging

  const int tid = threadIdx.x;
  const int wave = tid >> 6, lane = tid & 63;
  const int m16 = lane & 15, quad = lane >> 4;
  const int r = blockIdx.y;
  const int rowBase = blockIdx.x * 64;
  const int row = rowBase + wave * 16 + m16;
  const bool rowOK = row < M;

  const ushort* A  = inp + (size_t)r * aStride;
  const ushort* Wt = wt3 + (size_t)r * wStride;

  f32x4 acc[8];
  #pragma unroll
  for (int j = 0; j < 8; ++j)
    #pragma unroll
    for (int p = 0; p < 4; ++p) acc[j][p] = 0.f;

  uint4 pkAll[8];
  #pragma unroll
  for (int f = 0; f < 8; ++f) {
    uint4 pk = make_uint4(0u, 0u, 0u, 0u);
    if (rowOK) pk = *(const uint4*)(A + (size_t)row * 256 + f * 32 + quad * 8);
    pkAll[f] = pk;
  }

  #pragma unroll
  for (int c = 0; c < 4; ++c) {
    if (c) __syncthreads();
    #pragma unroll
    for (int i = 0; i < 4; ++i) {
      int q = tid + 256 * i;
      int col = ((q >> 6) & 7) * 16 + (q & 15);
      int kk  = c * 64 + ((q >> 9) & 1) * 32 + ((q >> 4) & 3) * 8;
      *(uint4*)&Ws[q * 8] = *(const uint4*)(Wt + (size_t)col * 256 + kk);
    }
    __syncthreads();
    #pragma unroll
    for (int ks = 0; ks < 2; ++ks) {
      s16x8 af = *(s16x8*)&pkAll[c * 2 + ks];
      #pragma unroll
      for (int j = 0; j < 8; ++j) {
        s16x8 bf = *(const s16x8*)&Ws[((ks * 8 + j) * 64 + lane) * 8];
        acc[j] = __builtin_amdgcn_mfma_f32_16x16x32_bf16(af, bf, acc[j], 0, 0, 0);
      }
    }
  }

  const float* bias = b3 + (size_t)r * 128;
  float bcol[8];
  #pragma unroll
  for (int j = 0; j < 8; ++j) bcol[j] = bias[j * 16 + m16];

  #pragma unroll
  for (int p = 0; p < 4; ++p) {
    int lrow = wave * 16 + quad * 4 + p;
    int grow = rowBase + lrow;
    bool ok = grow < M;
    float* Zr = z + (size_t)r * zStride + (size_t)grow * 128;
    #pragma unroll
    for (int j = 0; j < 8; ++j) {
      float v = ok ? acc[j][p] + bcol[j] : 0.f;
      if (ok) Zr[j * 16 + m16] = v;
      int byte = lrow * 256 + (j * 16 + m16) * 2;
      byte ^= (lrow & 7) << 4;
      *(ushort*)((char*)Zs + byte) = f2bf(v);
    }
  }

  f32x4 acc2[8];
  #pragma unroll
  for (int j = 0; j < 8; ++j)
    #pragma unroll
    for (int p = 0; p < 4; ++p) acc2[j][p] = 0.f;

  const int arow = wave * 16 + m16;
  #pragma unroll
  for (int c = 0; c < 2; ++c) {
    __syncthreads();
    #pragma unroll
    for (int i = 0; i < 4; ++i) {
      int q = tid + 256 * i;
      int col = ((q >> 6) & 7) * 16 + (q & 15);
      int kk  = c * 64 + ((q >> 9) & 1) * 32 + ((q >> 4) & 3) * 8;
      *(uint4*)&Ws[q * 8] = *(const uint4*)(w1t + (size_t)col * 128 + kk);
    }
    __syncthreads();
    #pragma unroll
    for (int ks = 0; ks < 2; ++ks) {
      int kk = c * 64 + ks * 32 + quad * 8;
      int byte = arow * 256 + kk * 2;
      byte ^= (arow & 7) << 4;
      s16x8 af = *(const s16x8*)((const char*)Zs + byte);
      #pragma unroll
      for (int j = 0; j < 8; ++j) {
        s16x8 bf = *(const s16x8*)&Ws[((ks * 8 + j) * 64 + lane) * 8];
        acc2[j] = __builtin_amdgcn_mfma_f32_16x16x32_bf16(af, bf, acc2[j], 0, 0, 0);
      }
    }
  }

  float b1c[8], w2c[8];
  #pragma unroll
  for (int j = 0; j < 8; ++j) { b1c[j] = b1[j * 16 + m16]; w2c[j] = w2[j * 16 + m16]; }

  float local = 0.f;
  #pragma unroll
  for (int p = 0; p < 4; ++p) {
    int grow = rowBase + wave * 16 + quad * 4 + p;
    if (grow >= M) continue;
    #pragma unroll
    for (int j = 0; j < 8; ++j)
      local += tanhf(acc2[j][p] + b1c[j]) * w2c[j];
  }
  #pragma unroll
  for (int o = 32; o > 0; o >>= 1) local += __shfl_down(local, o);
  __shared__ float red[4];
  if (lane == 0) red[wave] = local;
  __syncthreads();
  if (tid == 0) atomicAdd(&wsum[r], red[0] + red[1] + red[2] + red[3]);
}

// ---------------- unified CSR build: 6 (layer,relation) pairs ----------------
struct Csr6 {
  const int* edst0; const int* edst1;
  const int* esrc0; const int* esrc1;
  int E0, E1, N1, N2;
  int* deg;      // [3*N1 | 3*N2]  (also reused as fill cursor)
  int* rowptr;   // [3*(N1+1) | 3*(N2+1)]
  int* csr;      // [3*E0 | 3*E1]
};

__global__ void count_deg6(Csr6 c)
{
  int y = blockIdx.y, l = y / 3, r = y - l * 3;
  int E = l ? c.E1 : c.E0, N = l ? c.N2 : c.N1;
  const int* ed = l ? c.edst1 : c.edst0;
  int* deg = c.deg + (l ? 3 * c.N1 : 0) + r * N;
  int e = blockIdx.x * 256 + threadIdx.x;
  if (e < E) atomicAdd(&deg[ed[(size_t)r * E + e]], 1);
}

__global__ __launch_bounds__(1024) void scan_kernel6(Csr6 c)
{
  int y = blockIdx.y, l = y / 3, r = y - l * 3;
  int N = l ? c.N2 : c.N1;
  int* dgm = c.deg + (l ? 3 * c.N1 : 0) + r * N;   // deg in, cursor-zero out
  int* rp  = c.rowptr + (l ? 3 * (c.N1 + 1) : 0) + r * (N + 1);

  __shared__ int wtot[16];
  __shared__ int chunk_total_s;
  const int tid = threadIdx.x, lane = tid & 63, wid = tid >> 6;
  int running = 0;
  for (int base = 0; base < N; base += 4096) {
    int i0 = base + tid * 4;
    int d0 = 0, d1 = 0, d2 = 0, d3 = 0;
    if (i0 < N) {
      if (i0 + 3 < N) { int4 t = *(const int4*)(dgm + i0); d0 = t.x; d1 = t.y; d2 = t.z; d3 = t.w; }
      else { d0 = dgm[i0]; if (i0+1 < N) d1 = dgm[i0+1]; if (i0+2 < N) d2 = dgm[i0+2]; }
    }
    int tsum = d0 + d1 + d2 + d3;
    int incl = tsum;
    #pragma unroll
    for (int o = 1; o < 64; o <<= 1) {
      int t = __shfl_up(incl, o);
      if (lane >= o) incl += t;
    }
    if (lane == 63) wtot[wid] = incl;
    __syncthreads();
    if (wid == 0 && lane < 16) {
      int t = wtot[lane];
      int inc = t;
      #pragma unroll
      for (int o = 1; o < 16; o <<= 1) {
        int u = __shfl_up(inc, o);
        if (lane >= o) inc += u;
      }
      wtot[lane] = inc - t;
      if (lane == 15) chunk_total_s = inc;
    }
    __syncthreads();
    int excl = running + wtot[wid] + (incl - tsum);
    if (i0 < N) {
      int e1 = excl + d0, e2 = e1 + d1, e3 = e2 + d2;
      if (i0 + 3 < N) {
        *(int4*)(rp + i0) = make_int4(excl, e1, e2, e3);
        *(int4*)(dgm + i0) = make_int4(0, 0, 0, 0);
      } else {
        rp[i0] = excl; dgm[i0] = 0;
        if (i0+1 < N) { rp[i0+1] = e1; dgm[i0+1] = 0; }
        if (i0+2 < N) { rp[i0+2] = e2; dgm[i0+2] = 0; }
      }
    }
    running += chunk_total_s;
    __syncthreads();
  }
  if (tid == 0) rp[N] = running;
}

__global__ void fill_csr6(Csr6 c)
{
  int y = blockIdx.y, l = y / 3, r = y - l * 3;
  int E = l ? c.E1 : c.E0, N = l ? c.N2 : c.N1;
  const int* ed = l ? c.edst1 : c.edst0;
  const int* es = l ? c.esrc1 : c.esrc0;
  int* cur = c.deg + (l ? 3 * c.N1 : 0) + r * N;
  const int* rp = c.rowptr + (l ? 3 * (c.N1 + 1) : 0) + r * (N + 1);
  int* csr = c.csr + (l ? 3 * c.E0 : 0) + (size_t)r * E;
  int e = blockIdx.x * 256 + threadIdx.x;
  if (e >= E) return;
  int dn = ed[(size_t)r * E + e];
  int pos = atomicAdd(&cur[dn], 1);
  csr[rp[dn] + pos] = es[(size_t)r * E + e];
}

// one wave per (relation, chunk-local dst node): bf16 gather, x4-unrolled ILP
__global__ __launch_bounds__(256) void agg_kernel(
    const ushort* __restrict__ feat, const int* __restrict__ csr,
    const int* __restrict__ rowptr, int N, int c0, int cr, int CH, int E,
    ushort* __restrict__ aggS, ushort* __restrict__ aggM, float* __restrict__ invdeg)
{
  const int wid = threadIdx.x >> 6, lane = threadIdx.x & 63;
  const int node = blockIdx.x * 4 + wid;
  if (node >= cr) return;
  const size_t rp = (size_t)blockIdx.y * (N + 1) + c0 + node;
  const int o = blockIdx.y * CH + node;
  const int start = rowptr[rp], end = rowptr[rp + 1];
  const int* ecsr = csr + (size_t)blockIdx.y * E;
  const int j = lane * 4;
  float s0 = 0.f, s1 = 0.f, s2 = 0.f, s3 = 0.f;
  float m0 = -INFINITY, m1 = -INFINITY, m2 = -INFINITY, m3 = -INFINITY;
  int e = start;
  for (; e + 4 <= end; e += 4) {
    int sa = ecsr[e], sb = ecsr[e+1], sc = ecsr[e+2], sd = ecsr[e+3];
    uint2 va = *(const uint2*)(feat + (size_t)sa * 256 + j);
    uint2 vb = *(const uint2*)(feat + (size_t)sb * 256 + j);
    uint2 vc = *(const uint2*)(feat + (size_t)sc * 256 + j);
    uint2 vd = *(const uint2*)(feat + (size_t)sd * 256 + j);
    float a0, a1, a2, a3;
    a0 = bf2f(va.x & 0xFFFFu); a1 = bf2f(va.x >> 16); a2 = bf2f(va.y & 0xFFFFu); a3 = bf2f(va.y >> 16);
    s0 += a0; s1 += a1; s2 += a2; s3 += a3;
    m0 = fmaxf(m0, a0); m1 = fmaxf(m1, a1); m2 = fmaxf(m2, a2); m3 = fmaxf(m3, a3);
    a0 = bf2f(vb.x & 0xFFFFu); a1 = bf2f(vb.x >> 16); a2 = bf2f(vb.y & 0xFFFFu); a3 = bf2f(vb.y >> 16);
    s0 += a0; s1 += a1; s2 += a2; s3 += a3;
    m0 = fmaxf(m0, a0); m1 = fmaxf(m1, a1); m2 = fmaxf(m2, a2); m3 = fmaxf(m3, a3);
    a0 = bf2f(vc.x & 0xFFFFu); a1 = bf2f(vc.x >> 16); a2 = bf2f(vc.y & 0xFFFFu); a3 = bf2f(vc.y >> 16);
    s0 += a0; s1 += a1; s2 += a2; s3 += a3;
    m0 = fmaxf(m0, a0); m1 = fmaxf(m1, a1); m2 = fmaxf(m2, a2); m3 = fmaxf(m3, a3);
    a0 = bf2f(vd.x & 0xFFFFu); a1 = bf2f(vd.x >> 16); a2 = bf2f(vd.y & 0xFFFFu); a3 = bf2f(vd.y >> 16);
    s0 += a0; s1 += a1; s2 += a2; s3 += a3;
    m0 = fmaxf(m0, a0); m1 = fmaxf(m1, a1); m2 = fmaxf(m2, a2); m3 = fmaxf(m3, a3);
  }
  for (; e < end; ++e) {
    int src = ecsr[e];
    uint2 v = *(const uint2*)(feat + (size_t)src * 256 + j);
    float a0 = bf2f(v.x & 0xFFFFu), a1 = bf2f(v.x >> 16);
    float a2 = bf2f(v.y & 0xFFFFu), a3 = bf2f(v.y >> 16);
    s0 += a0; s1 += a1; s2 += a2; s3 += a3;
    m0 = fmaxf(m0, a0); m1 = fmaxf(m1, a1); m2 = fmaxf(m2, a2); m3 = fmaxf(m3, a3);
  }
  if (end == start) { m0 = m1 = m2 = m3 = 0.f; }
  uint2 ps; ps.x = pack2(s0, s1); ps.y = pack2(s2, s3);
  *(uint2*)(aggS + (size_t)o * 256 + j) = ps;
  uint2 pm; pm.x = pack2(m0, m1); pm.y = pack2(m2, m3);
  *(uint2*)(aggM + (size_t)o * 256 + j) = pm;
  if (lane == 0) invdeg[o] = 1.f / fmaxf((float)(end - start), 1.f);
}

// ---------------- combine (beta softmax computed in-kernel) ----------------
__device__ __forceinline__ void beta_from_wsum(const float* wsum, float invN,
                                               float& b0, float& b1, float& b2)
{
  float w0 = wsum[0] * invN, w1 = wsum[1] * invN, w2 = wsum[2] * invN;
  float m  = fmaxf(w0, fmaxf(w1, w2));
  float e0 = expf(w0 - m), e1 = expf(w1 - m), e2 = expf(w2 - m);
  float s  = 1.f / (e0 + e1 + e2);
  b0 = e0 * s; b1 = e1 * s; b2 = e2 * s;
}

// feat1 = bf16[relu(sum_r beta[r]*z1[r]) | tss[nid] | rs[nid]]; 8 nodes/block
__global__ __launch_bounds__(256) void combine1_kernel(
    const float* __restrict__ z1, const float* __restrict__ wsum, float invN,
    const float* __restrict__ tss, const float* __restrict__ rs,
    const int* __restrict__ nid, int N, ushort* __restrict__ feat1)
{
  int n = blockIdx.x * 8 + (threadIdx.x >> 5);
  int c = threadIdx.x & 31;
  if (n >= N) return;
  float b0, b1, b2;
  beta_from_wsum(wsum, invN, b0, b1, b2);
  size_t NH = (size_t)N * 128;
  const float* zp = z1 + (size_t)n * 128 + c * 4;
  float4 v0 = *(const float4*)zp;
  float4 v1 = *(const float4*)(zp + NH);
  float4 v2 = *(const float4*)(zp + 2 * NH);
  float wx = fmaxf(b0 * v0.x + b1 * v1.x + b2 * v2.x, 0.f);
  float wy = fmaxf(b0 * v0.y + b1 * v1.y + b2 * v2.y, 0.f);
  float wz = fmaxf(b0 * v0.z + b1 * v1.z + b2 * v2.z, 0.f);
  float ww = fmaxf(b0 * v0.w + b1 * v1.w + b2 * v2.w, 0.f);
  uint2 g; g.x = pack2(wx, wy); g.y = pack2(wz, ww);
  *(uint2*)(feat1 + (size_t)n * 256 + c * 4) = g;
  int id = nid[n];
  float4 t = (c < 16) ? *(const float4*)(tss + (size_t)id * 64 + c * 4)
                      : *(const float4*)(rs  + (size_t)id * 64 + (c - 16) * 4);
  uint2 g2; g2.x = pack2(t.x, t.y); g2.y = pack2(t.z, t.w);
  *(uint2*)(feat1 + (size_t)n * 256 + 128 + c * 4) = g2;
}

// out = sigmoid((sum_r beta[r]*z2[r]) @ pw + pb); 8 nodes/block, width-32 reduce
__global__ __launch_bounds__(256) void combine2_pred(
    const float* __restrict__ z2, const float* __restrict__ wsum, float invN,
    int N, const float* __restrict__ pw, const float* __restrict__ pb,
    float* __restrict__ out)
{
  int n = blockIdx.x * 8 + (threadIdx.x >> 5);
  int c = threadIdx.x & 31;
  bool ok = n < N;
  float p = 0.f;
  if (ok) {
    float b0, b1, b2;
    beta_from_wsum(wsum, invN, b0, b1, b2);
    size_t NH = (size_t)N * 128;
    const float* zp = z2 + (size_t)n * 128 + c * 4;
    float4 v0 = *(const float4*)zp;
    float4 v1 = *(const float4*)(zp + NH);
    float4 v2 = *(const float4*)(zp + 2 * NH);
    float4 w = *(const float4*)(pw + c * 4);
    p  = (b0 * v0.x + b1 * v1.x + b2 * v2.x) * w.x;
    p += (b0 * v0.y + b1 * v1.y + b2 * v2.y) * w.y;
    p += (b0 * v0.z + b1 * v1.z + b2 * v2.z) * w.z;
    p += (b0 * v0.w + b1 * v1.w + b2 * v2.w) * w.w;
  }
  #pragma unroll
  for (int o = 16; o > 0; o >>= 1) p += __shfl_down(p, o, 32);
  if (ok && c == 0) out[n] = 1.f / (1.f + expf(-(p + pb[0])));
}

extern "C" void kernel_launch(void* const* d_in, const int* in_sizes, int n_in,
                              void* d_out, int out_size, void* d_ws, size_t ws_size,
                              hipStream_t stream)
{
  const float* x_user  = (const float*)d_in[0];
  const float* tss     = (const float*)d_in[1];
  const float* rs      = (const float*)d_in[2];
  const int* src_nid0  = (const int*)d_in[3];
  const int* src_nid1  = (const int*)d_in[4];
  const int* e0_src    = (const int*)d_in[5];
  const int* e0_dst    = (const int*)d_in[6];
  const int* e1_src    = (const int*)d_in[7];
  const int* e1_dst    = (const int*)d_in[8];
  const float* embed_w = (const float*)d_in[9];
  const float* embed_b = (const float*)d_in[10];
  const float* l1w[3]  = {(const float*)d_in[11], (const float*)d_in[13], (const float*)d_in[15]};
  const float* l1b[3]  = {(const float*)d_in[12], (const float*)d_in[14], (const float*)d_in[16]};
  const float* l2w[3]  = {(const float*)d_in[17], (const float*)d_in[19], (const float*)d_in[21]};
  const float* l2b[3]  = {(const float*)d_in[18], (const float*)d_in[20], (const float*)d_in[22]};
  const float* attn_w1 = (const float*)d_in[23];
  const float* attn_b1 = (const float*)d_in[24];
  const float* attn_w2 = (const float*)d_in[25];
  const float* pred_w  = (const float*)d_in[26];
  const float* pred_b  = (const float*)d_in[27];
  float* out = (float*)d_out;

  const int N0 = in_sizes[0] / 128;
  const int N1 = in_sizes[4];
  const int N2 = out_size;
  const int E0 = in_sizes[5] / 3;
  const int E1 = in_sizes[7] / 3;

  char* wp = (char*)d_ws;
  auto walloc = [&](size_t bytes) {
    char* p = wp; wp += (bytes + 255) & ~(size_t)255; return p;
  };
  ushort* feat0  = (ushort*)walloc((size_t)N0 * 256 * 2);      // bf16
  ushort* inp    = (ushort*)walloc((size_t)3 * N1 * 256 * 2);  // bf16
  float*  z      = (float*)walloc((size_t)3 * N1 * 128 * 4);   // fp32
  ushort* wt_emb = (ushort*)walloc((size_t)128 * 128 * 2);
  ushort* wt_attn = (ushort*)walloc((size_t)128 * 128 * 2);
  ushort* wt_fc1[2], *wt_fc2[2], *wt_fc3[2];
  for (int l = 0; l < 2; ++l) {
    wt_fc1[l] = (ushort*)walloc((size_t)3 * 256 * 128 * 2);
    wt_fc2[l] = (ushort*)walloc((size_t)3 * 768 * 128 * 2);
    wt_fc3[l] = (ushort*)walloc((size_t)3 * 256 * 128 * 2);
  }
  // degcnt (both layers) immediately followed by small scratch -> one memset
  size_t degBytes = ((size_t)3 * (N1 + N2) * 4 + 255) & ~(size_t)255;
  int*   degcnt = (int*)walloc(degBytes);
  float* small  = (float*)walloc(256);
  int*   rowptr = (int*)walloc((size_t)(3 * (N1 + 1) + 3 * (N2 + 1)) * 4);
  int*   csr    = (int*)walloc((size_t)3 * (E0 + E1) * 4);
  float* wsum = small;              // [6]: 3 per layer
  ushort* feat1 = feat0;

  size_t used = (size_t)(wp - (char*)d_ws);
  size_t avail = (ws_size > used + 65536) ? (ws_size - used - 65536) : 0;
  const size_t per_row = (size_t)3 * (2 * 256 * 2 + 4 + 64);
  int CH = (int)(avail / per_row);
  if (CH > N1) CH = N1;
  if (CH < 1024) CH = 1024;
  ushort* aggS   = (ushort*)walloc((size_t)3 * CH * 256 * 2);
  ushort* aggM   = (ushort*)walloc((size_t)3 * CH * 256 * 2);
  float*  invdeg = (float*)walloc((size_t)3 * CH * 4);
  (void)n_in;

  // ---- single memset covers degcnt (both layers) + wsum scratch ----
  hipMemsetAsync(degcnt, 0, degBytes + 256, stream);

  // ---- weight prep ----
  {
    PrepAll P;
    P.src[0] = embed_w;  P.dst[0] = wt_emb;    P.K[0] = 128; P.total[0] = 128 * 128;
    P.src[1] = attn_w1;  P.dst[1] = wt_attn;   P.K[1] = 128; P.total[1] = 128 * 128;
    P.src[2] = l1w[0];   P.dst[2] = wt_fc1[0]; P.K[2] = 256; P.total[2] = 3 * 256 * 128;
    P.src[3] = l1w[1];   P.dst[3] = wt_fc2[0]; P.K[3] = 768; P.total[3] = 3 * 768 * 128;
    P.src[4] = l1w[2];   P.dst[4] = wt_fc3[0]; P.K[4] = 256; P.total[4] = 3 * 256 * 128;
    P.src[5] = l2w[0];   P.dst[5] = wt_fc1[1]; P.K[5] = 256; P.total[5] = 3 * 256 * 128;
    P.src[6] = l2w[1];   P.dst[6] = wt_fc2[1]; P.K[6] = 768; P.total[6] = 3 * 768 * 128;
    P.src[7] = l2w[2];   P.dst[7] = wt_fc3[1]; P.K[7] = 256; P.total[7] = 3 * 256 * 128;
    prep_all<<<dim3((3 * 768 * 128 + 255) / 256, 1, 8), 256, 0, stream>>>(P);
  }

  GemmDesc dz = {};
  dz.K = 256;

  // ---- feat0 = bf16[x@embed | tss | rs] (gather fused into epilogue) ----
  {
    GemmDesc d{};
    d.A = x_user; d.lda = 128; d.aStride = 0; d.aKind = 0;
    d.Wt = wt_emb; d.wStride = 0; d.bias = embed_b; d.biasStride = 0;
    d.C = feat0; d.ldc = 256; d.cStride = 0; d.cKind = 1;
    d.M = N0; d.K = 128; d.relu = 0;
    d.aggM = aggM; d.aggS = aggS; d.invdeg = invdeg; d.aggStride = 0; d.invStride = 0;
    d.gnid = src_nid0; d.gtss = tss; d.grs = rs;
    gemm_mfma<<<dim3((N0 + 63) / 64, 1, 1), 256, 0, stream>>>(d, dz);
  }

  // ---- unified CSR build for both layers (6 pairs) ----
  Csr6 c6;
  c6.edst0 = e0_dst; c6.edst1 = e1_dst;
  c6.esrc0 = e0_src; c6.esrc1 = e1_src;
  c6.E0 = E0; c6.E1 = E1; c6.N1 = N1; c6.N2 = N2;
  c6.deg = degcnt; c6.rowptr = rowptr; c6.csr = csr;
  {
    int Emax = E0 > E1 ? E0 : E1;
    count_deg6<<<dim3((Emax + 255) / 256, 6), 256, 0, stream>>>(c6);
    scan_kernel6<<<dim3(1, 6), 1024, 0, stream>>>(c6);
    fill_csr6<<<dim3((Emax + 255) / 256, 6), 256, 0, stream>>>(c6);
  }

  // ---- two conv layers ----
  for (int layer = 0; layer < 2; ++layer) {
    const ushort* featS = layer ? feat1 : feat0;
    int Nd = layer ? N2 : N1;
    int E  = layer ? E1 : E0;
    const float* const* lb = layer ? l2b : l1b;
    const int* rp_l  = rowptr + (layer ? 3 * (N1 + 1) : 0);
    const int* csr_l = csr + (layer ? 3 * E0 : 0);
    float* wsum_l = wsum + 3 * layer;

    for (int c0 = 0; c0 < Nd; c0 += CH) {
      int cr = (Nd - c0 < CH) ? (Nd - c0) : CH;
      agg_kernel<<<dim3((cr + 3) / 4, 3), 256, 0, stream>>>(
          featS, csr_l, rp_l, Nd, c0, cr, CH, E, aggS, aggM, invdeg);
      GemmDesc d2{};
      d2.A = nullptr; d2.lda = 0; d2.aStride = 0; d2.aKind = 2;
      d2.Wt = wt_fc2[layer]; d2.wStride = (size_t)768 * 128; d2.bias = lb[1]; d2.biasStride = 128;
      d2.C = inp + (size_t)c0 * 256; d2.ldc = 256; d2.cStride = (size_t)Nd * 256; d2.cKind = 1;
      d2.M = cr; d2.K = 768; d2.relu = 1;
      d2.aggM = aggM; d2.aggS = aggS; d2.invdeg = invdeg;
      d2.aggStride = (size_t)CH * 256; d2.invStride = CH;
      GemmDesc d1{};
      d1.A = featS + (size_t)c0 * 256; d1.lda = 256; d1.aStride = 0; d1.aKind = 1;
      d1.Wt = wt_fc1[layer]; d1.wStride = (size_t)256 * 128; d1.bias = lb[0]; d1.biasStride = 128;
      d1.C = inp + 128 + (size_t)c0 * 256; d1.ldc = 256; d1.cStride = (size_t)Nd * 256; d1.cKind = 1;
      d1.M = cr; d1.K = 256; d1.relu = 1;
      d1.aggM = aggM; d1.aggS = aggS; d1.invdeg = invdeg; d1.aggStride = 0; d1.invStride = 0;
      gemm_mfma<<<dim3((cr + 63) / 64, 3, 2), 256, 0, stream>>>(d2, d1);
    }

    fc3_attn<<<dim3((Nd + 63) / 64, 3), 256, 0, stream>>>(
        inp, (size_t)Nd * 256, wt_fc3[layer], (size_t)256 * 128, lb[2],
        z, (size_t)Nd * 128, Nd, wt_attn, attn_b1, attn_w2, wsum_l);

    if (layer == 0) {
      combine1_kernel<<<(N1 + 7) / 8, 256, 0, stream>>>(
          z, wsum_l, 1.0f / (float)N1, tss, rs, src_nid1, N1, feat1);
    } else {
      combine2_pred<<<(N2 + 7) / 8, 256, 0, stream>>>(
          z, wsum_l, 1.0f / (float)N2, N2, pred_w, pred_b, out);
    }
  }
}

// Round 8
// 486.942 us; speedup vs baseline: 1.0836x; 1.0223x over previous
//
#include <hip/hip_runtime.h>
#include <math.h>

// ---------------------------------------------------------------------------
// IG_RGCN forward on MI355X. Round 12:
//  - z ALIASED into dead tail of feat0 (rows >= N1 unused after L0 agg) ->
//    frees 30.7MB of workspace -> agg chunk CH grows (fewer serial
//    agg->gemm dispatch pairs if ws is small). Zero numerical change.
//  - embed_mfma: dedicated kernel; C-write now goes through a 16KB LDS tile
//    and stores coalesced uint4 rows (was 32 scalar 2-byte stores/thread).
//    A/B experiment on the write-coalescing theory, read out directly on the
//    one dispatch visible in top-5.
//  - gemm_mfma keeps only K=256/768 paths. All else unchanged from r11
//    (497.8 us).
// ---------------------------------------------------------------------------

typedef short s16x8 __attribute__((ext_vector_type(8)));
typedef float f32x4 __attribute__((ext_vector_type(4)));

__device__ __forceinline__ ushort f2bf(float f) {
  unsigned u = __float_as_uint(f);
  return (ushort)((u + 0x7FFFu + ((u >> 16) & 1u)) >> 16);
}
__device__ __forceinline__ float bf2f(unsigned hbits) {
  return __uint_as_float(hbits << 16);
}
__device__ __forceinline__ unsigned pack2(float lo, float hi) {
  return (unsigned)f2bf(lo) | ((unsigned)f2bf(hi) << 16);
}

// ---- one-shot weight prep: 8 tensors, W[r][K][128] fp32 -> Wt[r][128][K] bf16
struct PrepAll {
  const float* src[8];
  ushort* dst[8];
  int K[8];
  int total[8];
};

__global__ __launch_bounds__(256) void prep_all(PrepAll P)
{
  int t = blockIdx.z;
  int off = blockIdx.x * 256 + threadIdx.x;
  if (off >= P.total[t]) return;
  int K = P.K[t];
  int k = off % K;
  int n = (off / K) & 127;
  int r = off / (K * 128);
  P.dst[t][off] = f2bf(P.src[t][((size_t)r * K + k) * 128 + n]);
}

// ---- dedicated embed: feat0 = bf16[x@W+b | tss | rs], K=128, fp32 A.
// C-write via LDS tile -> coalesced uint4 stores (A/B vs scalar 2B stores).
__global__ __launch_bounds__(256) void embed_mfma(
    const float* __restrict__ A, const ushort* __restrict__ Wt,
    const float* __restrict__ bias, ushort* __restrict__ C, int M,
    const int* __restrict__ gnid, const float* __restrict__ gtss,
    const float* __restrict__ grs)
{
  __shared__ __align__(16) ushort Bs[1024 * 8];   // 16 KB B staging
  __shared__ __align__(16) ushort Cs[64 * 128];   // 16 KB C tile

  const int tid = threadIdx.x;
  const int wave = tid >> 6, lane = tid & 63;
  const int m16 = lane & 15, quad = lane >> 4;
  const int rowBase = blockIdx.x * 64;
  const int row = rowBase + wave * 16 + m16;
  const bool rowOK = row < M;

  f32x4 acc[8];
  #pragma unroll
  for (int j = 0; j < 8; ++j)
    #pragma unroll
    for (int p = 0; p < 4; ++p) acc[j][p] = 0.f;

  uint4 pkAll[4];
  #pragma unroll
  for (int f = 0; f < 4; ++f) {
    uint4 pk = make_uint4(0u, 0u, 0u, 0u);
    if (rowOK) {
      float4 fa = *(const float4*)(A + (size_t)row * 128 + f * 32 + quad * 8);
      float4 fb = *(const float4*)(A + (size_t)row * 128 + f * 32 + quad * 8 + 4);
      pk.x = pack2(fa.x, fa.y); pk.y = pack2(fa.z, fa.w);
      pk.z = pack2(fb.x, fb.y); pk.w = pack2(fb.z, fb.w);
    }
    pkAll[f] = pk;
  }

  #pragma unroll
  for (int c = 0; c < 2; ++c) {
    if (c) __syncthreads();
    #pragma unroll
    for (int i = 0; i < 4; ++i) {
      int q = tid + 256 * i;
      int col = ((q >> 6) & 7) * 16 + (q & 15);
      int kk  = c * 64 + ((q >> 9) & 1) * 32 + ((q >> 4) & 3) * 8;
      *(uint4*)&Bs[q * 8] = *(const uint4*)(Wt + (size_t)col * 128 + kk);
    }
    __syncthreads();
    #pragma unroll
    for (int ks = 0; ks < 2; ++ks) {
      s16x8 af = *(s16x8*)&pkAll[c * 2 + ks];
      #pragma unroll
      for (int j = 0; j < 8; ++j) {
        s16x8 bf = *(const s16x8*)&Bs[((ks * 8 + j) * 64 + lane) * 8];
        acc[j] = __builtin_amdgcn_mfma_f32_16x16x32_bf16(af, bf, acc[j], 0, 0, 0);
      }
    }
  }

  float bcol[8];
  #pragma unroll
  for (int j = 0; j < 8; ++j) bcol[j] = bias[j * 16 + m16];

  // acc -> LDS tile (linear [64][128])
  #pragma unroll
  for (int p = 0; p < 4; ++p) {
    int lrow = wave * 16 + quad * 4 + p;
    #pragma unroll
    for (int j = 0; j < 8; ++j)
      Cs[lrow * 128 + j * 16 + m16] = f2bf(acc[j][p] + bcol[j]);
  }
  __syncthreads();

  // coalesced C store: 1024 uint4 tasks (row = q>>4, 16B chunk = q&15)
  #pragma unroll
  for (int i = 0; i < 4; ++i) {
    int q = tid + 256 * i;
    int grow = rowBase + (q >> 4);
    if (grow < M)
      *(uint4*)(C + (size_t)grow * 256 + (q & 15) * 8) = *(const uint4*)&Cs[q * 8];
  }

  // fused gather: C cols 128..255 <- bf16(tss[nid] | rs[nid])
  #pragma unroll
  for (int i = 0; i < 8; ++i) {
    int q = tid + 256 * i;              // 2048 tasks: 64 rows x 32 chunks
    int grow = rowBase + (q >> 5);
    int c = q & 31;
    if (grow >= M) continue;
    int id = gnid[grow];
    float4 v = (c < 16) ? *(const float4*)(gtss + (size_t)id * 64 + c * 4)
                        : *(const float4*)(grs  + (size_t)id * 64 + (c - 16) * 4);
    uint2 g; g.x = pack2(v.x, v.y); g.y = pack2(v.z, v.w);
    *(uint2*)(C + (size_t)grow * 256 + 128 + c * 4) = g;
  }
}

struct GemmDesc {
  const void* A; int lda; size_t aStride; int aKind;   // 1 bf16, 2 virtual agg
  const ushort* Wt; size_t wStride;
  const float* bias; int biasStride;
  void* C; int ldc; size_t cStride; int cKind;         // 0 fp32, 1 bf16
  int M, K, relu;
  const ushort* aggM; const ushort* aggS; const float* invdeg;
  size_t aggStride; int invStride;
};

template<int AKIND>
__device__ __forceinline__ uint4 loadA(const void* Ab, const ushort* AgM,
                                       const ushort* AgS, int lda, int row,
                                       bool rowOK, int k0, int quad, float idg)
{
  uint4 pk = make_uint4(0u, 0u, 0u, 0u);
  if (rowOK) {
    if constexpr (AKIND == 1) {
      pk = *(const uint4*)((const ushort*)Ab + (size_t)row * lda + k0 + quad * 8);
    } else {                               // virtual [mx | sum*invdeg | sum]
      int seg = k0 >> 8;
      int jj  = (k0 & 255) + quad * 8;
      const ushort* Ag = (seg == 0) ? AgM : AgS;
      pk = *(const uint4*)(Ag + (size_t)row * 256 + jj);
      if (seg == 1) {
        pk.x = pack2(bf2f(pk.x & 0xFFFFu) * idg, bf2f(pk.x >> 16) * idg);
        pk.y = pack2(bf2f(pk.y & 0xFFFFu) * idg, bf2f(pk.y >> 16) * idg);
        pk.z = pack2(bf2f(pk.z & 0xFFFFu) * idg, bf2f(pk.z >> 16) * idg);
        pk.w = pack2(bf2f(pk.w & 0xFFFFu) * idg, bf2f(pk.w >> 16) * idg);
      }
    }
  }
  return pk;
}

// Core: C[M,128] = act(A[M,K] @ W + b). 64 rows/block, 16 rows/wave.
template<int K, int AKIND>
__device__ __forceinline__ void gemm_core(const GemmDesc& d, int r, ushort* Bs)
{
  constexpr int NC = K / 64;
  constexpr int NF = K / 32;

  const int tid = threadIdx.x;
  const int wave = tid >> 6, lane = tid & 63;
  const int m16 = lane & 15, quad = lane >> 4;
  const int rowBase = blockIdx.x * 64;
  const int row = rowBase + wave * 16 + m16;
  const bool rowOK = row < d.M;
  const ushort* Wt = d.Wt + (size_t)r * d.wStride;

  const void* Ab = (const char*)d.A + (size_t)r * d.aStride * sizeof(ushort);
  const ushort* AgM = d.aggM + (size_t)r * d.aggStride;
  const ushort* AgS = d.aggS + (size_t)r * d.aggStride;

  float idg = 1.f;
  if (AKIND == 2 && rowOK) idg = d.invdeg[(size_t)r * d.invStride + row];

  f32x4 acc[8];
  #pragma unroll
  for (int j = 0; j < 8; ++j)
    #pragma unroll
    for (int p = 0; p < 4; ++p) acc[j][p] = 0.f;

  uint4 pkAll[(K <= 256) ? NF : 2];
  if constexpr (K <= 256) {
    #pragma unroll
    for (int f = 0; f < NF; ++f)
      pkAll[f] = loadA<AKIND>(Ab, AgM, AgS, d.lda, row, rowOK, f * 32, quad, idg);
  }

  #pragma unroll
  for (int c = 0; c < NC; ++c) {
    if constexpr (K > 256) {
      pkAll[0] = loadA<AKIND>(Ab, AgM, AgS, d.lda, row, rowOK, c * 64,      quad, idg);
      pkAll[1] = loadA<AKIND>(Ab, AgM, AgS, d.lda, row, rowOK, c * 64 + 32, quad, idg);
    }
    if (c) __syncthreads();
    #pragma unroll
    for (int i = 0; i < 4; ++i) {
      int q = tid + 256 * i;
      int col = ((q >> 6) & 7) * 16 + (q & 15);
      int kk  = c * 64 + ((q >> 9) & 1) * 32 + ((q >> 4) & 3) * 8;
      *(uint4*)&Bs[q * 8] = *(const uint4*)(Wt + (size_t)col * K + kk);
    }
    __syncthreads();

    #pragma unroll
    for (int ks = 0; ks < 2; ++ks) {
      uint4 pk = (K <= 256) ? pkAll[c * 2 + ks] : pkAll[ks];
      s16x8 af = *(s16x8*)&pk;
      #pragma unroll
      for (int j = 0; j < 8; ++j) {
        s16x8 bf = *(const s16x8*)&Bs[((ks * 8 + j) * 64 + lane) * 8];
        acc[j] = __builtin_amdgcn_mfma_f32_16x16x32_bf16(af, bf, acc[j], 0, 0, 0);
      }
    }
  }

  const float* bias = d.bias + (size_t)r * d.biasStride;
  float bcol[8];
  #pragma unroll
  for (int j = 0; j < 8; ++j) bcol[j] = bias[j * 16 + m16];

  #pragma unroll
  for (int p = 0; p < 4; ++p) {
    int grow = rowBase + wave * 16 + quad * 4 + p;
    if (grow >= d.M) continue;
    if (d.cKind == 0) {
      float* Crow = (float*)d.C + (size_t)r * d.cStride + (size_t)grow * d.ldc;
      #pragma unroll
      for (int j = 0; j < 8; ++j) {
        float v = acc[j][p] + bcol[j];
        if (d.relu) v = fmaxf(v, 0.f);
        Crow[j * 16 + m16] = v;
      }
    } else {
      ushort* Crow = (ushort*)d.C + (size_t)r * d.cStride + (size_t)grow * d.ldc;
      #pragma unroll
      for (int j = 0; j < 8; ++j) {
        float v = acc[j][p] + bcol[j];
        if (d.relu) v = fmaxf(v, 0.f);
        Crow[j * 16 + m16] = f2bf(v);
      }
    }
  }
}

__global__ __launch_bounds__(256, 4) void gemm_mfma(GemmDesc d0, GemmDesc d1)
{
  __shared__ __align__(16) ushort Bs[1024 * 8];   // 16 KB
  const GemmDesc& d = blockIdx.z ? d1 : d0;
  const int r = blockIdx.y;
  if (d.K == 256)      gemm_core<256, 1>(d, r, Bs);
  else                 gemm_core<768, 2>(d, r, Bs);
}

// ---- fc3 + semantic attention fused (round 9 structure, verified).
__global__ __launch_bounds__(256) void fc3_attn(
    const ushort* __restrict__ inp, size_t aStride,
    const ushort* __restrict__ wt3, size_t wStride,
    const float* __restrict__ b3,
    float* __restrict__ z, size_t zStride, int M,
    const ushort* __restrict__ w1t, const float* __restrict__ b1,
    const float* __restrict__ w2, float* __restrict__ wsum)
{
  __shared__ __align__(16) ushort Zs[64 * 128];   // 16 KB bf16 z tile (swizzled)
  __shared__ __align__(16) ushort Ws[1024 * 8];   // 16 KB B staging

  const int tid = threadIdx.x;
  const int wave = tid >> 6, lane = tid & 63;
  const int m16 = lane & 15, quad = lane >> 4;
  const int r = blockIdx.y;
  const int rowBase = blockIdx.x * 64;
  const int row = rowBase + wave * 16 + m16;
  const bool rowOK = row < M;

  const ushort* A  = inp + (size_t)r * aStride;
  const ushort* Wt = wt3 + (size_t)r * wStride;

  f32x4 acc[8];
  #pragma unroll
  for (int j = 0; j < 8; ++j)
    #pragma unroll
    for (int p = 0; p < 4; ++p) acc[j][p] = 0.f;

  uint4 pkAll[8];
  #pragma unroll
  for (int f = 0; f < 8; ++f) {
    uint4 pk = make_uint4(0u, 0u, 0u, 0u);
    if (rowOK) pk = *(const uint4*)(A + (size_t)row * 256 + f * 32 + quad * 8);
    pkAll[f] = pk;
  }

  #pragma unroll
  for (int c = 0; c < 4; ++c) {
    if (c) __syncthreads();
    #pragma unroll
    for (int i = 0; i < 4; ++i) {
      int q = tid + 256 * i;
      int col = ((q >> 6) & 7) * 16 + (q & 15);
      int kk  = c * 64 + ((q >> 9) & 1) * 32 + ((q >> 4) & 3) * 8;
      *(uint4*)&Ws[q * 8] = *(const uint4*)(Wt + (size_t)col * 256 + kk);
    }
    __syncthreads();
    #pragma unroll
    for (int ks = 0; ks < 2; ++ks) {
      s16x8 af = *(s16x8*)&pkAll[c * 2 + ks];
      #pragma unroll
      for (int j = 0; j < 8; ++j) {
        s16x8 bf = *(const s16x8*)&Ws[((ks * 8 + j) * 64 + lane) * 8];
        acc[j] = __builtin_amdgcn_mfma_f32_16x16x32_bf16(af, bf, acc[j], 0, 0, 0);
      }
    }
  }

  const float* bias = b3 + (size_t)r * 128;
  float bcol[8];
  #pragma unroll
  for (int j = 0; j < 8; ++j) bcol[j] = bias[j * 16 + m16];

  #pragma unroll
  for (int p = 0; p < 4; ++p) {
    int lrow = wave * 16 + quad * 4 + p;
    int grow = rowBase + lrow;
    bool ok = grow < M;
    float* Zr = z + (size_t)r * zStride + (size_t)grow * 128;
    #pragma unroll
    for (int j = 0; j < 8; ++j) {
      float v = ok ? acc[j][p] + bcol[j] : 0.f;
      if (ok) Zr[j * 16 + m16] = v;
      int byte = lrow * 256 + (j * 16 + m16) * 2;
      byte ^= (lrow & 7) << 4;
      *(ushort*)((char*)Zs + byte) = f2bf(v);
    }
  }

  f32x4 acc2[8];
  #pragma unroll
  for (int j = 0; j < 8; ++j)
    #pragma unroll
    for (int p = 0; p < 4; ++p) acc2[j][p] = 0.f;

  const int arow = wave * 16 + m16;
  #pragma unroll
  for (int c = 0; c < 2; ++c) {
    __syncthreads();
    #pragma unroll
    for (int i = 0; i < 4; ++i) {
      int q = tid + 256 * i;
      int col = ((q >> 6) & 7) * 16 + (q & 15);
      int kk  = c * 64 + ((q >> 9) & 1) * 32 + ((q >> 4) & 3) * 8;
      *(uint4*)&Ws[q * 8] = *(const uint4*)(w1t + (size_t)col * 128 + kk);
    }
    __syncthreads();
    #pragma unroll
    for (int ks = 0; ks < 2; ++ks) {
      int kk = c * 64 + ks * 32 + quad * 8;
      int byte = arow * 256 + kk * 2;
      byte ^= (arow & 7) << 4;
      s16x8 af = *(const s16x8*)((const char*)Zs + byte);
      #pragma unroll
      for (int j = 0; j < 8; ++j) {
        s16x8 bf = *(const s16x8*)&Ws[((ks * 8 + j) * 64 + lane) * 8];
        acc2[j] = __builtin_amdgcn_mfma_f32_16x16x32_bf16(af, bf, acc2[j], 0, 0, 0);
      }
    }
  }

  float b1c[8], w2c[8];
  #pragma unroll
  for (int j = 0; j < 8; ++j) { b1c[j] = b1[j * 16 + m16]; w2c[j] = w2[j * 16 + m16]; }

  float local = 0.f;
  #pragma unroll
  for (int p = 0; p < 4; ++p) {
    int grow = rowBase + wave * 16 + quad * 4 + p;
    if (grow >= M) continue;
    #pragma unroll
    for (int j = 0; j < 8; ++j)
      local += tanhf(acc2[j][p] + b1c[j]) * w2c[j];
  }
  #pragma unroll
  for (int o = 32; o > 0; o >>= 1) local += __shfl_down(local, o);
  __shared__ float red[4];
  if (lane == 0) red[wave] = local;
  __syncthreads();
  if (tid == 0) atomicAdd(&wsum[r], red[0] + red[1] + red[2] + red[3]);
}

// ---------------- unified CSR build: 6 (layer,relation) pairs ----------------
struct Csr6 {
  const int* edst0; const int* edst1;
  const int* esrc0; const int* esrc1;
  int E0, E1, N1, N2;
  int* deg;      // [3*N1 | 3*N2]  (also reused as fill cursor)
  int* rowptr;   // [3*(N1+1) | 3*(N2+1)]
  int* csr;      // [3*E0 | 3*E1]
};

__global__ void count_deg6(Csr6 c)
{
  int y = blockIdx.y, l = y / 3, r = y - l * 3;
  int E = l ? c.E1 : c.E0, N = l ? c.N2 : c.N1;
  const int* ed = l ? c.edst1 : c.edst0;
  int* deg = c.deg + (l ? 3 * c.N1 : 0) + r * N;
  int e = blockIdx.x * 256 + threadIdx.x;
  if (e < E) atomicAdd(&deg[ed[(size_t)r * E + e]], 1);
}

__global__ __launch_bounds__(1024) void scan_kernel6(Csr6 c)
{
  int y = blockIdx.y, l = y / 3, r = y - l * 3;
  int N = l ? c.N2 : c.N1;
  int* dgm = c.deg + (l ? 3 * c.N1 : 0) + r * N;   // deg in, cursor-zero out
  int* rp  = c.rowptr + (l ? 3 * (c.N1 + 1) : 0) + r * (N + 1);

  __shared__ int wtot[16];
  __shared__ int chunk_total_s;
  const int tid = threadIdx.x, lane = tid & 63, wid = tid >> 6;
  int running = 0;
  for (int base = 0; base < N; base += 4096) {
    int i0 = base + tid * 4;
    int d0 = 0, d1 = 0, d2 = 0, d3 = 0;
    if (i0 < N) {
      if (i0 + 3 < N) { int4 t = *(const int4*)(dgm + i0); d0 = t.x; d1 = t.y; d2 = t.z; d3 = t.w; }
      else { d0 = dgm[i0]; if (i0+1 < N) d1 = dgm[i0+1]; if (i0+2 < N) d2 = dgm[i0+2]; }
    }
    int tsum = d0 + d1 + d2 + d3;
    int incl = tsum;
    #pragma unroll
    for (int o = 1; o < 64; o <<= 1) {
      int t = __shfl_up(incl, o);
      if (lane >= o) incl += t;
    }
    if (lane == 63) wtot[wid] = incl;
    __syncthreads();
    if (wid == 0 && lane < 16) {
      int t = wtot[lane];
      int inc = t;
      #pragma unroll
      for (int o = 1; o < 16; o <<= 1) {
        int u = __shfl_up(inc, o);
        if (lane >= o) inc += u;
      }
      wtot[lane] = inc - t;
      if (lane == 15) chunk_total_s = inc;
    }
    __syncthreads();
    int excl = running + wtot[wid] + (incl - tsum);
    if (i0 < N) {
      int e1 = excl + d0, e2 = e1 + d1, e3 = e2 + d2;
      if (i0 + 3 < N) {
        *(int4*)(rp + i0) = make_int4(excl, e1, e2, e3);
        *(int4*)(dgm + i0) = make_int4(0, 0, 0, 0);
      } else {
        rp[i0] = excl; dgm[i0] = 0;
        if (i0+1 < N) { rp[i0+1] = e1; dgm[i0+1] = 0; }
        if (i0+2 < N) { rp[i0+2] = e2; dgm[i0+2] = 0; }
      }
    }
    running += chunk_total_s;
    __syncthreads();
  }
  if (tid == 0) rp[N] = running;
}

__global__ void fill_csr6(Csr6 c)
{
  int y = blockIdx.y, l = y / 3, r = y - l * 3;
  int E = l ? c.E1 : c.E0, N = l ? c.N2 : c.N1;
  const int* ed = l ? c.edst1 : c.edst0;
  const int* es = l ? c.esrc1 : c.esrc0;
  int* cur = c.deg + (l ? 3 * c.N1 : 0) + r * N;
  const int* rp = c.rowptr + (l ? 3 * (c.N1 + 1) : 0) + r * (N + 1);
  int* csr = c.csr + (l ? 3 * c.E0 : 0) + (size_t)r * E;
  int e = blockIdx.x * 256 + threadIdx.x;
  if (e >= E) return;
  int dn = ed[(size_t)r * E + e];
  int pos = atomicAdd(&cur[dn], 1);
  csr[rp[dn] + pos] = es[(size_t)r * E + e];
}

// one wave per (relation, chunk-local dst node): bf16 gather, x4-unrolled ILP
__global__ __launch_bounds__(256) void agg_kernel(
    const ushort* __restrict__ feat, const int* __restrict__ csr,
    const int* __restrict__ rowptr, int N, int c0, int cr, int CH, int E,
    ushort* __restrict__ aggS, ushort* __restrict__ aggM, float* __restrict__ invdeg)
{
  const int wid = threadIdx.x >> 6, lane = threadIdx.x & 63;
  const int node = blockIdx.x * 4 + wid;
  if (node >= cr) return;
  const size_t rp = (size_t)blockIdx.y * (N + 1) + c0 + node;
  const int o = blockIdx.y * CH + node;
  const int start = rowptr[rp], end = rowptr[rp + 1];
  const int* ecsr = csr + (size_t)blockIdx.y * E;
  const int j = lane * 4;
  float s0 = 0.f, s1 = 0.f, s2 = 0.f, s3 = 0.f;
  float m0 = -INFINITY, m1 = -INFINITY, m2 = -INFINITY, m3 = -INFINITY;
  int e = start;
  for (; e + 4 <= end; e += 4) {
    int sa = ecsr[e], sb = ecsr[e+1], sc = ecsr[e+2], sd = ecsr[e+3];
    uint2 va = *(const uint2*)(feat + (size_t)sa * 256 + j);
    uint2 vb = *(const uint2*)(feat + (size_t)sb * 256 + j);
    uint2 vc = *(const uint2*)(feat + (size_t)sc * 256 + j);
    uint2 vd = *(const uint2*)(feat + (size_t)sd * 256 + j);
    float a0, a1, a2, a3;
    a0 = bf2f(va.x & 0xFFFFu); a1 = bf2f(va.x >> 16); a2 = bf2f(va.y & 0xFFFFu); a3 = bf2f(va.y >> 16);
    s0 += a0; s1 += a1; s2 += a2; s3 += a3;
    m0 = fmaxf(m0, a0); m1 = fmaxf(m1, a1); m2 = fmaxf(m2, a2); m3 = fmaxf(m3, a3);
    a0 = bf2f(vb.x & 0xFFFFu); a1 = bf2f(vb.x >> 16); a2 = bf2f(vb.y & 0xFFFFu); a3 = bf2f(vb.y >> 16);
    s0 += a0; s1 += a1; s2 += a2; s3 += a3;
    m0 = fmaxf(m0, a0); m1 = fmaxf(m1, a1); m2 = fmaxf(m2, a2); m3 = fmaxf(m3, a3);
    a0 = bf2f(vc.x & 0xFFFFu); a1 = bf2f(vc.x >> 16); a2 = bf2f(vc.y & 0xFFFFu); a3 = bf2f(vc.y >> 16);
    s0 += a0; s1 += a1; s2 += a2; s3 += a3;
    m0 = fmaxf(m0, a0); m1 = fmaxf(m1, a1); m2 = fmaxf(m2, a2); m3 = fmaxf(m3, a3);
    a0 = bf2f(vd.x & 0xFFFFu); a1 = bf2f(vd.x >> 16); a2 = bf2f(vd.y & 0xFFFFu); a3 = bf2f(vd.y >> 16);
    s0 += a0; s1 += a1; s2 += a2; s3 += a3;
    m0 = fmaxf(m0, a0); m1 = fmaxf(m1, a1); m2 = fmaxf(m2, a2); m3 = fmaxf(m3, a3);
  }
  for (; e < end; ++e) {
    int src = ecsr[e];
    uint2 v = *(const uint2*)(feat + (size_t)src * 256 + j);
    float a0 = bf2f(v.x & 0xFFFFu), a1 = bf2f(v.x >> 16);
    float a2 = bf2f(v.y & 0xFFFFu), a3 = bf2f(v.y >> 16);
    s0 += a0; s1 += a1; s2 += a2; s3 += a3;
    m0 = fmaxf(m0, a0); m1 = fmaxf(m1, a1); m2 = fmaxf(m2, a2); m3 = fmaxf(m3, a3);
  }
  if (end == start) { m0 = m1 = m2 = m3 = 0.f; }
  uint2 ps; ps.x = pack2(s0, s1); ps.y = pack2(s2, s3);
  *(uint2*)(aggS + (size_t)o * 256 + j) = ps;
  uint2 pm; pm.x = pack2(m0, m1); pm.y = pack2(m2, m3);
  *(uint2*)(aggM + (size_t)o * 256 + j) = pm;
  if (lane == 0) invdeg[o] = 1.f / fmaxf((float)(end - start), 1.f);
}

// ---------------- combine (beta softmax computed in-kernel) ----------------
__device__ __forceinline__ void beta_from_wsum(const float* wsum, float invN,
                                               float& b0, float& b1, float& b2)
{
  float w0 = wsum[0] * invN, w1 = wsum[1] * invN, w2 = wsum[2] * invN;
  float m  = fmaxf(w0, fmaxf(w1, w2));
  float e0 = expf(w0 - m), e1 = expf(w1 - m), e2 = expf(w2 - m);
  float s  = 1.f / (e0 + e1 + e2);
  b0 = e0 * s; b1 = e1 * s; b2 = e2 * s;
}

// feat1 = bf16[relu(sum_r beta[r]*z1[r]) | tss[nid] | rs[nid]]; 8 nodes/block
__global__ __launch_bounds__(256) void combine1_kernel(
    const float* __restrict__ z1, const float* __restrict__ wsum, float invN,
    const float* __restrict__ tss, const float* __restrict__ rs,
    const int* __restrict__ nid, int N, ushort* __restrict__ feat1)
{
  int n = blockIdx.x * 8 + (threadIdx.x >> 5);
  int c = threadIdx.x & 31;
  if (n >= N) return;
  float b0, b1, b2;
  beta_from_wsum(wsum, invN, b0, b1, b2);
  size_t NH = (size_t)N * 128;
  const float* zp = z1 + (size_t)n * 128 + c * 4;
  float4 v0 = *(const float4*)zp;
  float4 v1 = *(const float4*)(zp + NH);
  float4 v2 = *(const float4*)(zp + 2 * NH);
  float wx = fmaxf(b0 * v0.x + b1 * v1.x + b2 * v2.x, 0.f);
  float wy = fmaxf(b0 * v0.y + b1 * v1.y + b2 * v2.y, 0.f);
  float wz = fmaxf(b0 * v0.z + b1 * v1.z + b2 * v2.z, 0.f);
  float ww = fmaxf(b0 * v0.w + b1 * v1.w + b2 * v2.w, 0.f);
  uint2 g; g.x = pack2(wx, wy); g.y = pack2(wz, ww);
  *(uint2*)(feat1 + (size_t)n * 256 + c * 4) = g;
  int id = nid[n];
  float4 t = (c < 16) ? *(const float4*)(tss + (size_t)id * 64 + c * 4)
                      : *(const float4*)(rs  + (size_t)id * 64 + (c - 16) * 4);
  uint2 g2; g2.x = pack2(t.x, t.y); g2.y = pack2(t.z, t.w);
  *(uint2*)(feat1 + (size_t)n * 256 + 128 + c * 4) = g2;
}

// out = sigmoid((sum_r beta[r]*z2[r]) @ pw + pb); 8 nodes/block, width-32 reduce
__global__ __launch_bounds__(256) void combine2_pred(
    const float* __restrict__ z2, const float* __restrict__ wsum, float invN,
    int N, const float* __restrict__ pw, const float* __restrict__ pb,
    float* __restrict__ out)
{
  int n = blockIdx.x * 8 + (threadIdx.x >> 5);
  int c = threadIdx.x & 31;
  bool ok = n < N;
  float p = 0.f;
  if (ok) {
    float b0, b1, b2;
    beta_from_wsum(wsum, invN, b0, b1, b2);
    size_t NH = (size_t)N * 128;
    const float* zp = z2 + (size_t)n * 128 + c * 4;
    float4 v0 = *(const float4*)zp;
    float4 v1 = *(const float4*)(zp + NH);
    float4 v2 = *(const float4*)(zp + 2 * NH);
    float4 w = *(const float4*)(pw + c * 4);
    p  = (b0 * v0.x + b1 * v1.x + b2 * v2.x) * w.x;
    p += (b0 * v0.y + b1 * v1.y + b2 * v2.y) * w.y;
    p += (b0 * v0.z + b1 * v1.z + b2 * v2.z) * w.z;
    p += (b0 * v0.w + b1 * v1.w + b2 * v2.w) * w.w;
  }
  #pragma unroll
  for (int o = 16; o > 0; o >>= 1) p += __shfl_down(p, o, 32);
  if (ok && c == 0) out[n] = 1.f / (1.f + expf(-(p + pb[0])));
}

extern "C" void kernel_launch(void* const* d_in, const int* in_sizes, int n_in,
                              void* d_out, int out_size, void* d_ws, size_t ws_size,
                              hipStream_t stream)
{
  const float* x_user  = (const float*)d_in[0];
  const float* tss     = (const float*)d_in[1];
  const float* rs      = (const float*)d_in[2];
  const int* src_nid0  = (const int*)d_in[3];
  const int* src_nid1  = (const int*)d_in[4];
  const int* e0_src    = (const int*)d_in[5];
  const int* e0_dst    = (const int*)d_in[6];
  const int* e1_src    = (const int*)d_in[7];
  const int* e1_dst    = (const int*)d_in[8];
  const float* embed_w = (const float*)d_in[9];
  const float* embed_b = (const float*)d_in[10];
  const float* l1w[3]  = {(const float*)d_in[11], (const float*)d_in[13], (const float*)d_in[15]};
  const float* l1b[3]  = {(const float*)d_in[12], (const float*)d_in[14], (const float*)d_in[16]};
  const float* l2w[3]  = {(const float*)d_in[17], (const float*)d_in[19], (const float*)d_in[21]};
  const float* l2b[3]  = {(const float*)d_in[18], (const float*)d_in[20], (const float*)d_in[22]};
  const float* attn_w1 = (const float*)d_in[23];
  const float* attn_b1 = (const float*)d_in[24];
  const float* attn_w2 = (const float*)d_in[25];
  const float* pred_w  = (const float*)d_in[26];
  const float* pred_b  = (const float*)d_in[27];
  float* out = (float*)d_out;

  const int N0 = in_sizes[0] / 128;
  const int N1 = in_sizes[4];
  const int N2 = out_size;
  const int E0 = in_sizes[5] / 3;
  const int E1 = in_sizes[7] / 3;

  char* wp = (char*)d_ws;
  auto walloc = [&](size_t bytes) {
    char* p = wp; wp += (bytes + 255) & ~(size_t)255; return p;
  };
  ushort* feat0  = (ushort*)walloc((size_t)N0 * 256 * 2);      // bf16
  ushort* inp    = (ushort*)walloc((size_t)3 * N1 * 256 * 2);  // bf16
  ushort* wt_emb = (ushort*)walloc((size_t)128 * 128 * 2);
  ushort* wt_attn = (ushort*)walloc((size_t)128 * 128 * 2);
  ushort* wt_fc1[2], *wt_fc2[2], *wt_fc3[2];
  for (int l = 0; l < 2; ++l) {
    wt_fc1[l] = (ushort*)walloc((size_t)3 * 256 * 128 * 2);
    wt_fc2[l] = (ushort*)walloc((size_t)3 * 768 * 128 * 2);
    wt_fc3[l] = (ushort*)walloc((size_t)3 * 256 * 128 * 2);
  }
  size_t degBytes = ((size_t)3 * (N1 + N2) * 4 + 255) & ~(size_t)255;
  int*   degcnt = (int*)walloc(degBytes);
  float* small  = (float*)walloc(256);
  int*   rowptr = (int*)walloc((size_t)(3 * (N1 + 1) + 3 * (N2 + 1)) * 4);
  int*   csr    = (int*)walloc((size_t)3 * (E0 + E1) * 4);
  float* wsum = small;              // [6]: 3 per layer
  ushort* feat1 = feat0;

  // z aliased into the dead tail of feat0 (rows >= N1 unused after L0 agg).
  // z written by fc3_attn (after all agg chunks), read by combine; disjoint
  // from feat1 rows [0,N1). Falls back to a real alloc if the tail is small.
  size_t zBytes   = (size_t)3 * ((N1 > N2) ? N1 : N2) * 128 * 4;
  size_t tailBytes = (N0 > N1) ? ((size_t)(N0 - N1) * 512) : 0;
  float* z;
  if (tailBytes >= zBytes)
    z = (float*)((char*)feat0 + (size_t)N1 * 512);
  else
    z = (float*)walloc(zBytes);

  size_t used = (size_t)(wp - (char*)d_ws);
  size_t avail = (ws_size > used + 65536) ? (ws_size - used - 65536) : 0;
  const size_t per_row = (size_t)3 * (2 * 256 * 2 + 4);   // aggS+aggM+invdeg
  int CH = (int)(avail / per_row);
  if (CH > N1) CH = N1;
  if (CH < 1024) CH = 1024;
  ushort* aggS   = (ushort*)walloc((size_t)3 * CH * 256 * 2);
  ushort* aggM   = (ushort*)walloc((size_t)3 * CH * 256 * 2);
  float*  invdeg = (float*)walloc((size_t)3 * CH * 4);
  (void)n_in;

  // ---- single memset covers degcnt (both layers) + wsum scratch ----
  hipMemsetAsync(degcnt, 0, degBytes + 256, stream);

  // ---- weight prep ----
  {
    PrepAll P;
    P.src[0] = embed_w;  P.dst[0] = wt_emb;    P.K[0] = 128; P.total[0] = 128 * 128;
    P.src[1] = attn_w1;  P.dst[1] = wt_attn;   P.K[1] = 128; P.total[1] = 128 * 128;
    P.src[2] = l1w[0];   P.dst[2] = wt_fc1[0]; P.K[2] = 256; P.total[2] = 3 * 256 * 128;
    P.src[3] = l1w[1];   P.dst[3] = wt_fc2[0]; P.K[3] = 768; P.total[3] = 3 * 768 * 128;
    P.src[4] = l1w[2];   P.dst[4] = wt_fc3[0]; P.K[4] = 256; P.total[4] = 3 * 256 * 128;
    P.src[5] = l2w[0];   P.dst[5] = wt_fc1[1]; P.K[5] = 256; P.total[5] = 3 * 256 * 128;
    P.src[6] = l2w[1];   P.dst[6] = wt_fc2[1]; P.K[6] = 768; P.total[6] = 3 * 768 * 128;
    P.src[7] = l2w[2];   P.dst[7] = wt_fc3[1]; P.K[7] = 256; P.total[7] = 3 * 256 * 128;
    prep_all<<<dim3((3 * 768 * 128 + 255) / 256, 1, 8), 256, 0, stream>>>(P);
  }

  // ---- feat0 = bf16[x@embed | tss | rs] (dedicated kernel, LDS-coalesced C) ----
  embed_mfma<<<dim3((N0 + 63) / 64), 256, 0, stream>>>(
      x_user, wt_emb, embed_b, feat0, N0, src_nid0, tss, rs);

  // ---- unified CSR build for both layers (6 pairs) ----
  Csr6 c6;
  c6.edst0 = e0_dst; c6.edst1 = e1_dst;
  c6.esrc0 = e0_src; c6.esrc1 = e1_src;
  c6.E0 = E0; c6.E1 = E1; c6.N1 = N1; c6.N2 = N2;
  c6.deg = degcnt; c6.rowptr = rowptr; c6.csr = csr;
  {
    int Emax = E0 > E1 ? E0 : E1;
    count_deg6<<<dim3((Emax + 255) / 256, 6), 256, 0, stream>>>(c6);
    scan_kernel6<<<dim3(1, 6), 1024, 0, stream>>>(c6);
    fill_csr6<<<dim3((Emax + 255) / 256, 6), 256, 0, stream>>>(c6);
  }

  // ---- two conv layers ----
  for (int layer = 0; layer < 2; ++layer) {
    const ushort* featS = layer ? feat1 : feat0;
    int Nd = layer ? N2 : N1;
    int E  = layer ? E1 : E0;
    const float* const* lb = layer ? l2b : l1b;
    const int* rp_l  = rowptr + (layer ? 3 * (N1 + 1) : 0);
    const int* csr_l = csr + (layer ? 3 * E0 : 0);
    float* wsum_l = wsum + 3 * layer;

    for (int c0 = 0; c0 < Nd; c0 += CH) {
      int cr = (Nd - c0 < CH) ? (Nd - c0) : CH;
      agg_kernel<<<dim3((cr + 3) / 4, 3), 256, 0, stream>>>(
          featS, csr_l, rp_l, Nd, c0, cr, CH, E, aggS, aggM, invdeg);
      GemmDesc d2{};
      d2.A = nullptr; d2.lda = 0; d2.aStride = 0; d2.aKind = 2;
      d2.Wt = wt_fc2[layer]; d2.wStride = (size_t)768 * 128; d2.bias = lb[1]; d2.biasStride = 128;
      d2.C = inp + (size_t)c0 * 256; d2.ldc = 256; d2.cStride = (size_t)Nd * 256; d2.cKind = 1;
      d2.M = cr; d2.K = 768; d2.relu = 1;
      d2.aggM = aggM; d2.aggS = aggS; d2.invdeg = invdeg;
      d2.aggStride = (size_t)CH * 256; d2.invStride = CH;
      GemmDesc d1{};
      d1.A = featS + (size_t)c0 * 256; d1.lda = 256; d1.aStride = 0; d1.aKind = 1;
      d1.Wt = wt_fc1[layer]; d1.wStride = (size_t)256 * 128; d1.bias = lb[0]; d1.biasStride = 128;
      d1.C = inp + 128 + (size_t)c0 * 256; d1.ldc = 256; d1.cStride = (size_t)Nd * 256; d1.cKind = 1;
      d1.M = cr; d1.K = 256; d1.relu = 1;
      d1.aggM = aggM; d1.aggS = aggS; d1.invdeg = invdeg; d1.aggStride = 0; d1.invStride = 0;
      gemm_mfma<<<dim3((cr + 63) / 64, 3, 2), 256, 0, stream>>>(d2, d1);
    }

    fc3_attn<<<dim3((Nd + 63) / 64, 3), 256, 0, stream>>>(
        inp, (size_t)Nd * 256, wt_fc3[layer], (size_t)256 * 128, lb[2],
        z, (size_t)Nd * 128, Nd, wt_attn, attn_b1, attn_w2, wsum_l);

    if (layer == 0) {
      combine1_kernel<<<(N1 + 7) / 8, 256, 0, stream>>>(
          z, wsum_l, 1.0f / (float)N1, tss, rs, src_nid1, N1, feat1);
    } else {
      combine2_pred<<<(N2 + 7) / 8, 256, 0, stream>>>(
          z, wsum_l, 1.0f / (float)N2, N2, pred_w, pred_b, out);
    }
  }
}